// Round 10
// baseline (333.651 us; speedup 1.0000x reference)
//
#include <hip/hip_runtime.h>
#include <hip/hip_bf16.h>
#include <stdint.h>

#define NTOK 196
#define NB   64
#define CCH  512
#define HID  2048
#define MTOT (NB * NTOK)   // 12544

typedef __attribute__((ext_vector_type(8))) short  short8v;
typedef __attribute__((ext_vector_type(4))) float  float4v;

// ---------------- helpers ----------------

__device__ __forceinline__ void mfma16x16(float4v& d, short8v a, short8v b) {
  asm("v_mfma_f32_16x16x32_bf16 %0, %1, %2, %0" : "+v"(d) : "v"(a), "v"(b));
}

__device__ __forceinline__ void gload_lds16(const void* gsrc, void* ldst) {
  __builtin_amdgcn_global_load_lds(
      (const __attribute__((address_space(1))) unsigned int*)gsrc,
      (__attribute__((address_space(3))) unsigned int*)ldst, 16, 0, 0);
}

__device__ __forceinline__ int swz4(int r) { return (r ^ (r >> 2)) & 3; }

// ---------------- calibration kernels (scratch-only, overwritten later) ----------------

// Pure-MFMA throughput probe: 512 blocks x 4 waves, 6144 MFMAs/wave on register data.
// Model: per SIMD 2 waves x 6144 x ~4.85cy ~= 60K cy ~= 25 us at 2.4 GHz / 256 CUs.
__global__ __launch_bounds__(256) void cal_mfma(float* __restrict__ out) {
  short8v a;
  #pragma unroll
  for (int i = 0; i < 8; ++i) a[i] = (short)(threadIdx.x + 3 * i + 1);
  float4v a0 = {0.f, 0.f, 0.f, 0.f};
  float4v a1 = {0.f, 0.f, 0.f, 0.f};
  #pragma unroll 8
  for (int i = 0; i < 3072; ++i) {
    mfma16x16(a0, a, a);
    mfma16x16(a1, a, a);
  }
  asm volatile("s_nop 7\n\ts_nop 7");
  float4v r;
  #pragma unroll
  for (int e = 0; e < 4; ++e) r[e] = a0[e] + a1[e];
  *(float4v*)(out + (size_t)(blockIdx.x * 256 + threadIdx.x) * 4) = r;
}

// Pure-HBM stream probe: copy x (25.7 MB) -> scratch. Model ~8 us at 6.3 TB/s.
__global__ __launch_bounds__(256) void cal_copy(const float4v* __restrict__ src,
                                                float4v* __restrict__ dst, int n4) {
  int i = blockIdx.x * blockDim.x + threadIdx.x;
  const int stride = gridDim.x * blockDim.x;
  for (; i < n4; i += stride) dst[i] = src[i];
}

// ---------------- prep: BN constants ----------------

__global__ void prep_consts(const float* __restrict__ bn_g, const float* __restrict__ bn_b,
                            const float* __restrict__ bn_m, const float* __restrict__ bn_v,
                            const float* __restrict__ fbn_g, const float* __restrict__ fbn_b,
                            const float* __restrict__ fbn_m, const float* __restrict__ fbn_v,
                            float* __restrict__ cst) {
  int c = blockIdx.x * blockDim.x + threadIdx.x;
  if (c < CCH) {
    float i1 = bn_g[c] * rsqrtf(bn_v[c] + 1e-5f);
    cst[c] = i1;
    cst[512 + c] = bn_b[c] - bn_m[c] * i1;
    float i2 = fbn_g[c] * rsqrtf(fbn_v[c] + 1e-5f);
    cst[1024 + c] = i2;
    cst[1536 + c] = fbn_b[c] - fbn_m[c] * i2;
  }
}

// ---------------- weights fp32 -> bf16 ----------------

__global__ void cvt_weights(const float* __restrict__ qkv_w, const float* __restrict__ proj_w,
                            const float* __restrict__ fc1_w, const float* __restrict__ fc2_w,
                            __hip_bfloat16* __restrict__ qkvb, __hip_bfloat16* __restrict__ projb,
                            __hip_bfloat16* __restrict__ fc1b, __hip_bfloat16* __restrict__ fc2b) {
  int i4 = blockIdx.x * blockDim.x + threadIdx.x;    // unit = 4 floats
  const int nq = 1536 * 512 / 4;
  const int np = 512 * 512 / 4;
  const int n1 = 2048 * 512 / 4;
  const float* src;
  __hip_bfloat16* dst;
  int k;
  if (i4 < nq)                { src = qkv_w;  dst = qkvb;  k = i4; }
  else if (i4 < nq + np)      { src = proj_w; dst = projb; k = i4 - nq; }
  else if (i4 < nq + np + n1) { src = fc1_w;  dst = fc1b;  k = i4 - nq - np; }
  else                        { src = fc2_w;  dst = fc2b;  k = i4 - nq - np - n1; }
  float4v v = *(const float4v*)(src + 4 * (size_t)k);
  #pragma unroll
  for (int l = 0; l < 4; ++l) dst[4 * (size_t)k + l] = __float2bfloat16(v[l]);
}

// ---------------- transpose NCHW fp32 -> token-major bf16 (raw + BN'd) ----------------

__global__ __launch_bounds__(256) void transpose_x(
    const float* __restrict__ x, __hip_bfloat16* __restrict__ xnt,
    __hip_bfloat16* __restrict__ xt, const float* __restrict__ cst) {
  __shared__ float tile[32][33];
  const int n0 = blockIdx.x * 32;
  const int c0 = blockIdx.y * 32;
  const int b  = blockIdx.z;
  const int j = threadIdx.x & 31, i = threadIdx.x >> 5;
  #pragma unroll
  for (int p = 0; p < 4; ++p) {
    int cc = c0 + i + p * 8;
    int n = n0 + j;
    if (n < NTOK) tile[i + p * 8][j] = x[((size_t)b * CCH + cc) * NTOK + n];
  }
  __syncthreads();
  const float s = cst[c0 + j], t = cst[512 + c0 + j];
  #pragma unroll
  for (int p = 0; p < 4; ++p) {
    int n = n0 + i + p * 8;
    int cc = c0 + j;
    if (n < NTOK) {
      float raw = tile[j][i + p * 8];
      size_t o = ((size_t)b * NTOK + n) * CCH + cc;
      xt[o]  = __float2bfloat16(raw);
      xnt[o] = __float2bfloat16(raw * s + t);
    }
  }
}

// ---------------- GEMM (R2-proven): C[M,N] = A[M,K]*B[N,K]^T, bf16, fp32 acc ----------------
// Triple-buffered, counted-vmcnt pipeline, raw s_barrier. (best-measured family: ~84-88us)
// EPI: 0 = plain bf16 store (QKV)
//      1 = proj: x1t = xt + ls1*(v+bias)            (token-major bf16)
//      2 = fc1:  gelu(v+bias) bf16                  (token-major)
//      3 = fc2:  out = x1t + ls2*(v+bias) -> NCHW fp32 via in-LDS transpose

template<int EPI>
__global__ __launch_bounds__(256, 3) void gemm_bt(
    const __hip_bfloat16* __restrict__ A, const __hip_bfloat16* __restrict__ Bw,
    int N, int K, int NY,
    __hip_bfloat16* __restrict__ outb, float* __restrict__ outf,
    const float* __restrict__ bias, const float* __restrict__ ls,
    const __hip_bfloat16* __restrict__ resid) {
  __shared__ char lds[49152];   // 3 bufs x (A 8KB + B 8KB)
  const int tid  = threadIdx.x;
  const int lane = tid & 63;
  const int wave = tid >> 6;

  // bijective XCD swizzle (nwg % 8 == 0 for all our grids), y-fastest linearization
  const int q    = (int)gridDim.x >> 3;
  const int orig = blockIdx.x;
  const int wgid = (orig & 7) * q + (orig >> 3);
  const int bx = wgid / NY;
  const int by = wgid - bx * NY;

  const int m0 = bx * 128;
  const int n0 = by * 128;
  const int wm = (wave >> 1) * 64;
  const int wn = (wave & 1) * 64;
  const int KT = K >> 5;

  float4v acc[4][4] = {};

  auto stage = [&](int buf, int kt) {
    const int kb = kt * 32;
    char* base = lds + buf * 16384;
    #pragma unroll
    for (int i = 0; i < 2; ++i) {
      int L = i * 4096 + tid * 16;
      int row = L >> 6;
      int kc = ((L >> 4) & 3) ^ swz4(row);
      gload_lds16(A + (size_t)(m0 + row) * K + kb + kc * 8, base + L);
    }
    #pragma unroll
    for (int i = 0; i < 2; ++i) {
      int L = i * 4096 + tid * 16;
      int row = L >> 6;
      int kc = ((L >> 4) & 3) ^ swz4(row);
      gload_lds16(Bw + (size_t)(n0 + row) * K + kb + kc * 8, base + 8192 + L);
    }
  };

  auto compute = [&](int buf) {
    const char* bA = lds + buf * 16384;
    const char* bB = bA + 8192;
    short8v av[4], bv[4];
    #pragma unroll
    for (int t = 0; t < 4; ++t) {
      int row = wm + t * 16 + (lane & 15);
      int pc = (lane >> 4) ^ swz4(row);
      av[t] = *(const short8v*)(bA + row * 64 + pc * 16);
    }
    #pragma unroll
    for (int t = 0; t < 4; ++t) {
      int row = wn + t * 16 + (lane & 15);
      int pc = (lane >> 4) ^ swz4(row);
      bv[t] = *(const short8v*)(bB + row * 64 + pc * 16);
    }
    #pragma unroll
    for (int i = 0; i < 4; ++i)
      #pragma unroll
      for (int j = 0; j < 4; ++j)
        mfma16x16(acc[i][j], av[i], bv[j]);
  };

  // prologue: 2 tiles in flight (8 gload_lds per wave)
  stage(0, 0);
  stage(1, 1);
  int cur = 0;
  for (int kt = 0; kt < KT - 1; ++kt) {
    asm volatile("s_waitcnt vmcnt(4)" ::: "memory");   // oldest stage (buf cur) complete
    __builtin_amdgcn_s_barrier();                       // all waves' cur-stage complete
    __builtin_amdgcn_sched_barrier(0);
    if (kt + 2 < KT) {
      int s = cur + 2; if (s >= 3) s -= 3;
      stage(s, kt + 2);
    }
    compute(cur);
    ++cur; if (cur == 3) cur = 0;
  }
  asm volatile("s_waitcnt vmcnt(0)" ::: "memory");
  __builtin_amdgcn_s_barrier();
  __builtin_amdgcn_sched_barrier(0);
  compute(cur);
  asm volatile("s_nop 7\n\ts_nop 7");      // MFMA->VALU hazard guard

  if (EPI == 0 || EPI == 2) {
    #pragma unroll
    for (int i = 0; i < 4; ++i)
      #pragma unroll
      for (int j = 0; j < 4; ++j)
        #pragma unroll
        for (int r = 0; r < 4; ++r) {
          int m = m0 + wm + i * 16 + ((lane >> 4) << 2) + r;
          int n = n0 + wn + j * 16 + (lane & 15);
          float v = acc[i][j][r];
          if (EPI == 0) {
            outb[(size_t)m * N + n] = __float2bfloat16(v);
          } else {
            float z = v + bias[n];
            float g = 0.5f * z * (1.0f + erff(z * 0.70710678118654752f));
            outb[(size_t)m * N + n] = __float2bfloat16(g);
          }
        }
  } else if (EPI == 1) {
    #pragma unroll
    for (int i = 0; i < 4; ++i)
      #pragma unroll
      for (int j = 0; j < 4; ++j)
        #pragma unroll
        for (int r = 0; r < 4; ++r) {
          int m = m0 + wm + i * 16 + ((lane >> 4) << 2) + r;
          int n = n0 + wn + j * 16 + (lane & 15);
          float v = acc[i][j][r] + bias[n];
          v = __bfloat162float(resid[(size_t)m * CCH + n]) + ls[n] * v;
          outb[(size_t)m * CCH + n] = __float2bfloat16(v);
        }
  } else {   // EPI == 3 : fused epilogue + in-LDS transpose -> NCHW fp32
    float* LT = (float*)lds;   // [64][129] fp32
    #pragma unroll 1
    for (int hh = 0; hh < 2; ++hh) {
      __syncthreads();
      if ((wn >> 6) == hh) {
        #pragma unroll
        for (int i = 0; i < 4; ++i)
          #pragma unroll
          for (int j = 0; j < 4; ++j)
            #pragma unroll
            for (int r = 0; r < 4; ++r) {
              int ml = wm + i * 16 + ((lane >> 4) << 2) + r;
              int nl = j * 16 + (lane & 15);
              int n = n0 + wn + nl;
              float v = acc[i][j][r] + bias[n];
              v = __bfloat162float(resid[(size_t)(m0 + ml) * CCH + n]) + ls[n] * v;
              LT[nl * 129 + ml] = v;
            }
      }
      __syncthreads();
      {
        int ml0 = lane << 1;
        int mg = m0 + ml0;
        int bb0 = mg / NTOK;
        int tt0 = mg - bb0 * NTOK;
        int bb1 = (mg + 1) / NTOK;
        int tt1 = (mg + 1) - bb1 * NTOK;
        size_t base0 = (size_t)bb0 * (CCH * NTOK) + tt0;
        size_t base1 = (size_t)bb1 * (CCH * NTOK) + tt1;
        #pragma unroll
        for (int u = 0; u < 16; ++u) {
          int cr = wave * 16 + u;
          int cg = n0 + hh * 64 + cr;
          float v0 = LT[cr * 129 + ml0];
          float v1 = LT[cr * 129 + ml0 + 1];
          outf[base0 + (size_t)cg * NTOK] = v0;
          outf[base1 + (size_t)cg * NTOK] = v1;
        }
      }
    }
  }
}

// ---------------- attention: one block per (batch, head) ----------------

__global__ __launch_bounds__(256, 2) void attn_kernel(
    const __hip_bfloat16* __restrict__ qkv, __hip_bfloat16* __restrict__ o_t) {
  __shared__ char sQ[208 * 64];    // [208][32] bf16, chunk-swizzled rows
  __shared__ char sK[224 * 64];    // [224][32] bf16
  __shared__ char sV[32 * 448];    // V^T [32][224] bf16, chunk-swizzled
  __shared__ char sP[4][16 * 472]; // per-wave P [16][236] bf16
  const int tid  = threadIdx.x;
  const int lane = tid & 63;
  const int wave = tid >> 6;
  const int b = blockIdx.x >> 4;
  const int h = blockIdx.x & 15;
  const size_t qbase = (size_t)b * NTOK * 1536 + h * 32;

  {
    uint32_t* z = (uint32_t*)sQ;
    for (int i = tid; i < (208 * 64) / 4; i += 256) z[i] = 0u;
    z = (uint32_t*)sK;
    for (int i = tid; i < (224 * 64) / 4; i += 256) z[i] = 0u;
    z = (uint32_t*)sV;
    for (int i = tid; i < (32 * 448) / 4; i += 256) z[i] = 0u;
  }
  __syncthreads();

  for (int p = tid; p < NTOK * 4; p += 256) {
    int row = p >> 2, c = p & 3;
    const __hip_bfloat16* src = qkv + qbase + (size_t)row * 1536 + c * 8;
    short8v q = *(const short8v*)(src);
    short8v k = *(const short8v*)(src + 512);
    short8v v = *(const short8v*)(src + 1024);
    int pc = c ^ swz4(row);
    *(short8v*)(sQ + row * 64 + pc * 16) = q;
    *(short8v*)(sK + row * 64 + pc * 16) = k;
    #pragma unroll
    for (int j = 0; j < 8; ++j) {
      int d = c * 8 + j;
      int ch = (row >> 3) ^ swz4(d);
      *(uint16_t*)(sV + d * 448 + ch * 16 + (row & 7) * 2) = (uint16_t)v[j];
    }
  }
  __syncthreads();

  const float scale = 0.17677669529663687f;   // 1/sqrt(32)
  char* Pw = sP[wave];

  for (int mt = wave; mt < 13; mt += 4) {
    int qrow = mt * 16 + (lane & 15);
    int pcq = (lane >> 4) ^ swz4(qrow);
    short8v aq = *(const short8v*)(sQ + qrow * 64 + pcq * 16);

    float4v s[14];
    #pragma unroll
    for (int nt = 0; nt < 14; ++nt) {
      int krow = nt * 16 + (lane & 15);
      int pck = (lane >> 4) ^ swz4(krow);
      short8v bk = *(const short8v*)(sK + krow * 64 + pck * 16);
      s[nt] = float4v{0.f, 0.f, 0.f, 0.f};
      mfma16x16(s[nt], aq, bk);
    }
    asm volatile("s_nop 7\n\ts_nop 7");

    float mx[4] = {-INFINITY, -INFINITY, -INFINITY, -INFINITY};
    #pragma unroll
    for (int nt = 0; nt < 14; ++nt) {
      bool valid = (nt * 16 + (lane & 15)) < NTOK;
      #pragma unroll
      for (int r = 0; r < 4; ++r) {
        float v = valid ? s[nt][r] * scale : -INFINITY;
        s[nt][r] = v;
        mx[r] = fmaxf(mx[r], v);
      }
    }
    #pragma unroll
    for (int off = 1; off < 16; off <<= 1) {
      #pragma unroll
      for (int r = 0; r < 4; ++r) mx[r] = fmaxf(mx[r], __shfl_xor(mx[r], off));
    }
    float sum[4] = {0.f, 0.f, 0.f, 0.f};
    #pragma unroll
    for (int nt = 0; nt < 14; ++nt) {
      #pragma unroll
      for (int r = 0; r < 4; ++r) {
        float e = __expf(s[nt][r] - mx[r]);
        s[nt][r] = e;
        sum[r] += e;
      }
    }
    #pragma unroll
    for (int off = 1; off < 16; off <<= 1) {
      #pragma unroll
      for (int r = 0; r < 4; ++r) sum[r] += __shfl_xor(sum[r], off);
    }
    float rs[4];
    #pragma unroll
    for (int r = 0; r < 4; ++r) rs[r] = 1.0f / sum[r];

    #pragma unroll
    for (int nt = 0; nt < 14; ++nt) {
      int col = nt * 16 + (lane & 15);
      #pragma unroll
      for (int r = 0; r < 4; ++r) {
        int prow = ((lane >> 4) << 2) + r;
        *(__hip_bfloat16*)(Pw + prow * 472 + col * 2) = __float2bfloat16(s[nt][r] * rs[r]);
      }
    }

    float4v o0 = float4v{0.f, 0.f, 0.f, 0.f};
    float4v o1 = float4v{0.f, 0.f, 0.f, 0.f};
    #pragma unroll
    for (int ks = 0; ks < 7; ++ks) {
      short8v pa = *(const short8v*)(Pw + (lane & 15) * 472 + ks * 64 + ((lane >> 4) << 4));
      int kc = ks * 4 + (lane >> 4);
      int d0 = (lane & 15);
      int d1 = 16 + (lane & 15);
      short8v v0 = *(const short8v*)(sV + d0 * 448 + ((kc ^ swz4(d0)) << 4));
      short8v v1 = *(const short8v*)(sV + d1 * 448 + ((kc ^ swz4(d1)) << 4));
      mfma16x16(o0, pa, v0);
      mfma16x16(o1, pa, v1);
    }
    asm volatile("s_nop 7\n\ts_nop 7");

    #pragma unroll
    for (int r = 0; r < 4; ++r) {
      int trow = mt * 16 + ((lane >> 4) << 2) + r;
      if (trow < NTOK) {
        size_t ob = ((size_t)b * NTOK + trow) * CCH + h * 32 + (lane & 15);
        o_t[ob] = __float2bfloat16(o0[r]);
        o_t[ob + 16] = __float2bfloat16(o1[r]);
      }
    }
  }
}

// ---------------- depthwise 7x7 conv, token-major (+BN in, +fBN out) ----------------

__global__ __launch_bounds__(448) void dwconv_tm(
    const __hip_bfloat16* __restrict__ x1t, const float* __restrict__ dw_w,
    const float* __restrict__ cst, __hip_bfloat16* __restrict__ yt) {
  __shared__ float img[196][32];
  __shared__ float wgt[49][32];
  const int tid = threadIdx.x;
  const int b  = blockIdx.x >> 4;
  const int cb = (blockIdx.x & 15) * 32;
  const int c  = tid & 31;
  const int gc = cb + c;
  const float s = cst[gc], t0 = cst[512 + gc];
  #pragma unroll
  for (int k = 0; k < 14; ++k) {
    int p = (tid >> 5) + k * 14;
    img[p][c] = __bfloat162float(x1t[((size_t)b * NTOK + p) * CCH + gc]) * s + t0;
  }
  for (int i = tid; i < 49 * 32; i += 448) {
    int tap = i >> 5, cc = i & 31;
    wgt[tap][cc] = dw_w[(cb + cc) * 49 + tap];
  }
  __syncthreads();

  const int px = tid >> 5;        // 0..13
  float out[14];
  #pragma unroll
  for (int i = 0; i < 14; ++i) out[i] = 0.f;
  #pragma unroll 1
  for (int row = 0; row < 14; ++row) {
    float v[7];
    #pragma unroll
    for (int dx = 0; dx < 7; ++dx) {
      int ix = px + dx - 3;
      v[dx] = ((unsigned)ix < 14u) ? img[row * 14 + ix][c] : 0.f;
    }
    #pragma unroll
    for (int kk = 0; kk < 7; ++kk) {
      int py = row + 3 - kk;
      if (py >= 0 && py < 14) {
        float hsum = 0.f;
        #pragma unroll
        for (int dx = 0; dx < 7; ++dx) hsum = fmaf(v[dx], wgt[kk * 7 + dx][c], hsum);
        out[py] += hsum;
      }
    }
  }
  const float fs = cst[1024 + gc], ft = cst[1536 + gc];
  #pragma unroll
  for (int py = 0; py < 14; ++py)
    yt[((size_t)b * NTOK + py * 14 + px) * CCH + gc] = __float2bfloat16(out[py] * fs + ft);
}

// ---------------- launch ----------------

extern "C" void kernel_launch(void* const* d_in, const int* in_sizes, int n_in,
                              void* d_out, int out_size, void* d_ws, size_t ws_size,
                              hipStream_t stream) {
  const float* x      = (const float*)d_in[0];
  const float* bn_g   = (const float*)d_in[1];
  const float* bn_b   = (const float*)d_in[2];
  const float* bn_m   = (const float*)d_in[3];
  const float* bn_v   = (const float*)d_in[4];
  const float* qkv_w  = (const float*)d_in[5];
  const float* proj_w = (const float*)d_in[6];
  const float* proj_b = (const float*)d_in[7];
  const float* dw_w   = (const float*)d_in[8];
  const float* fbn_g  = (const float*)d_in[9];
  const float* fbn_b  = (const float*)d_in[10];
  const float* fbn_m  = (const float*)d_in[11];
  const float* fbn_v  = (const float*)d_in[12];
  const float* fc1_w  = (const float*)d_in[13];
  const float* fc1_b  = (const float*)d_in[14];
  const float* fc2_w  = (const float*)d_in[15];
  const float* fc2_b  = (const float*)d_in[16];
  const float* ls1    = (const float*)d_in[17];
  const float* ls2    = (const float*)d_in[18];

  char* ws = (char*)d_ws;
  float* cst             = (float*)ws;                       // 8 KB
  __hip_bfloat16* qkvb   = (__hip_bfloat16*)(ws + 8192);
  __hip_bfloat16* projb  = (__hip_bfloat16*)(ws + 1581056);
  __hip_bfloat16* fc1b   = (__hip_bfloat16*)(ws + 2105344);
  __hip_bfloat16* fc2b   = (__hip_bfloat16*)(ws + 4202496);
  __hip_bfloat16* xnt    = (__hip_bfloat16*)(ws + 6299648);   // 12.85 MB
  __hip_bfloat16* xt     = (__hip_bfloat16*)(ws + 19144704);  // 12.85 MB
  __hip_bfloat16* qkvt   = (__hip_bfloat16*)(ws + 31989760);  // 38.5 MB
  __hip_bfloat16* ot     = (__hip_bfloat16*)(ws + 70524928);  // 12.85 MB
  __hip_bfloat16* x1t    = (__hip_bfloat16*)(ws + 83369984);  // 12.85 MB
  __hip_bfloat16* yt     = (__hip_bfloat16*)(ws + 96215040);  // 12.85 MB (end 109060096)
  __hip_bfloat16* hbuf   = (__hip_bfloat16*)(ws + 6299648);   // 51.4 MB overlay (xnt/xt/qkvt dead)

  // ---- calibration (scratch region = qkvt, fully rewritten by QKV GEMM below) ----
  cal_copy<<<dim3(2048), dim3(256), 0, stream>>>((const float4v*)x, (float4v*)qkvt,
                                                 (NB * CCH * NTOK) / 4);   // 25.7 MB copy
  cal_mfma<<<dim3(512), dim3(256), 0, stream>>>((float*)(ws + 31989760 + 27000000));

  prep_consts<<<dim3(2), dim3(256), 0, stream>>>(bn_g, bn_b, bn_m, bn_v,
                                                 fbn_g, fbn_b, fbn_m, fbn_v, cst);
  cvt_weights<<<dim3(3072), dim3(256), 0, stream>>>(qkv_w, proj_w, fc1_w, fc2_w,
                                                    qkvb, projb, fc1b, fc2b);
  transpose_x<<<dim3(7, 16, 64), dim3(256), 0, stream>>>(x, xnt, xt, cst);
  // QKV: M=12544, N=1536, K=512 ; grid 98*12 = 1176
  gemm_bt<0><<<dim3(1176), dim3(256), 0, stream>>>(xnt, qkvb, 1536, 512, 12,
                                                   qkvt, nullptr, nullptr, nullptr, nullptr);
  attn_kernel<<<dim3(1024), dim3(256), 0, stream>>>(qkvt, ot);
  // proj: N=512, K=512 ; grid 98*4 = 392
  gemm_bt<1><<<dim3(392), dim3(256), 0, stream>>>(ot, projb, 512, 512, 4,
                                                  x1t, nullptr, proj_b, ls1, xt);
  dwconv_tm<<<dim3(1024), dim3(448), 0, stream>>>(x1t, dw_w, cst, yt);
  // fc1: N=2048, K=512 ; grid 98*16 = 1568
  gemm_bt<2><<<dim3(1568), dim3(256), 0, stream>>>(yt, fc1b, 2048, 512, 16,
                                                   hbuf, nullptr, fc1_b, nullptr, nullptr);
  // fc2: N=512, K=2048 ; grid 98*4 = 392 ; writes NCHW fp32 d_out
  gemm_bt<3><<<dim3(392), dim3(256), 0, stream>>>(hbuf, fc2b, 512, 2048, 4,
                                                  nullptr, (float*)d_out, fc2_b, ls2, x1t);
}

// Round 11
// 278.521 us; speedup vs baseline: 1.1979x; 1.1979x over previous
//
#include <hip/hip_runtime.h>
#include <hip/hip_bf16.h>
#include <stdint.h>

#define NTOK 196
#define NB   64
#define CCH  512
#define HID  2048
#define MTOT (NB * NTOK)   // 12544

typedef __attribute__((ext_vector_type(8))) short  short8v;
typedef __attribute__((ext_vector_type(4))) float  float4v;

// ---------------- helpers ----------------

__device__ __forceinline__ void mfma16x16(float4v& d, short8v a, short8v b) {
  asm("v_mfma_f32_16x16x32_bf16 %0, %1, %2, %0" : "+v"(d) : "v"(a), "v"(b));
}

__device__ __forceinline__ void gload_lds16(const void* gsrc, void* ldst) {
  __builtin_amdgcn_global_load_lds(
      (const __attribute__((address_space(1))) unsigned int*)gsrc,
      (__attribute__((address_space(3))) unsigned int*)ldst, 16, 0, 0);
}

__device__ __forceinline__ int swz4(int r) { return (r ^ (r >> 2)) & 3; }

// ---------------- prep: BN constants ----------------

__global__ void prep_consts(const float* __restrict__ bn_g, const float* __restrict__ bn_b,
                            const float* __restrict__ bn_m, const float* __restrict__ bn_v,
                            const float* __restrict__ fbn_g, const float* __restrict__ fbn_b,
                            const float* __restrict__ fbn_m, const float* __restrict__ fbn_v,
                            float* __restrict__ cst) {
  int c = blockIdx.x * blockDim.x + threadIdx.x;
  if (c < CCH) {
    float i1 = bn_g[c] * rsqrtf(bn_v[c] + 1e-5f);
    cst[c] = i1;
    cst[512 + c] = bn_b[c] - bn_m[c] * i1;
    float i2 = fbn_g[c] * rsqrtf(fbn_v[c] + 1e-5f);
    cst[1024 + c] = i2;
    cst[1536 + c] = fbn_b[c] - fbn_m[c] * i2;
  }
}

// ---------------- weights fp32 -> bf16 ----------------

__global__ void cvt_weights(const float* __restrict__ qkv_w, const float* __restrict__ proj_w,
                            const float* __restrict__ fc1_w, const float* __restrict__ fc2_w,
                            __hip_bfloat16* __restrict__ qkvb, __hip_bfloat16* __restrict__ projb,
                            __hip_bfloat16* __restrict__ fc1b, __hip_bfloat16* __restrict__ fc2b) {
  int i4 = blockIdx.x * blockDim.x + threadIdx.x;    // unit = 4 floats
  const int nq = 1536 * 512 / 4;
  const int np = 512 * 512 / 4;
  const int n1 = 2048 * 512 / 4;
  const float* src;
  __hip_bfloat16* dst;
  int k;
  if (i4 < nq)                { src = qkv_w;  dst = qkvb;  k = i4; }
  else if (i4 < nq + np)      { src = proj_w; dst = projb; k = i4 - nq; }
  else if (i4 < nq + np + n1) { src = fc1_w;  dst = fc1b;  k = i4 - nq - np; }
  else                        { src = fc2_w;  dst = fc2b;  k = i4 - nq - np - n1; }
  float4v v = *(const float4v*)(src + 4 * (size_t)k);
  #pragma unroll
  for (int l = 0; l < 4; ++l) dst[4 * (size_t)k + l] = __float2bfloat16(v[l]);
}

// ---------------- transpose NCHW fp32 -> token-major bf16 (raw + BN'd) ----------------

__global__ __launch_bounds__(256) void transpose_x(
    const float* __restrict__ x, __hip_bfloat16* __restrict__ xnt,
    __hip_bfloat16* __restrict__ xt, const float* __restrict__ cst) {
  __shared__ float tile[32][33];
  const int n0 = blockIdx.x * 32;
  const int c0 = blockIdx.y * 32;
  const int b  = blockIdx.z;
  const int j = threadIdx.x & 31, i = threadIdx.x >> 5;
  #pragma unroll
  for (int p = 0; p < 4; ++p) {
    int cc = c0 + i + p * 8;
    int n = n0 + j;
    if (n < NTOK) tile[i + p * 8][j] = x[((size_t)b * CCH + cc) * NTOK + n];
  }
  __syncthreads();
  const float s = cst[c0 + j], t = cst[512 + c0 + j];
  #pragma unroll
  for (int p = 0; p < 4; ++p) {
    int n = n0 + i + p * 8;
    int cc = c0 + j;
    if (n < NTOK) {
      float raw = tile[j][i + p * 8];
      size_t o = ((size_t)b * NTOK + n) * CCH + cc;
      xt[o]  = __float2bfloat16(raw);
      xnt[o] = __float2bfloat16(raw * s + t);
    }
  }
}

// ---------------- 8-phase 256-row GEMM (m201 recipe): C = A[M,K]*B[N,K]^T ----------------
// BM=256, BN in {256,128}; 512 thr = 8 waves. BN=256: waves 2Mx4N (per-wave 128x64,
// MREP=8); BN=128: waves 4Mx2N (per-wave 64x64, MREP=4). BK=64, dbuf LDS.
// Per phase: ds_read quadrant (+B at q0) | stage one 16KB piece | barrier |
// lgkmcnt(0)+sched_barrier | setprio(1) | MFMA cluster | setprio(0) | barrier.
// vmcnt counted (4 / 2), only at phases 3 and 7 - never drains mid-loop.
// EPI: 0 = bf16 (QKV)   1 = proj: x1t = xt + ls1*(v+bias)
//      2 = fc1 gelu     3 = fc2: out = x1t + ls2*(v+bias) -> NCHW fp32 (LDS transpose)

template<int BN, int EPI>
__global__ __launch_bounds__(512, 2) void gemm8p(
    const __hip_bfloat16* __restrict__ A, const __hip_bfloat16* __restrict__ Bw,
    int N, int K, int NY,
    __hip_bfloat16* __restrict__ outb, float* __restrict__ outf,
    const float* __restrict__ bias, const float* __restrict__ ls,
    const __hip_bfloat16* __restrict__ resid) {
  constexpr int BUFSZ = 32768 + BN * 128;          // A 32KB + B BN*64*2B
  __shared__ char lds[2 * BUFSZ];
  const int tid  = threadIdx.x;
  const int lane = tid & 63;
  const int wave = tid >> 6;

  // bijective XCD swizzle (m204); by-fast within wgid -> A-panel L2 sharing
  const int nwg = (int)gridDim.x;
  const int q8 = nwg >> 3, r8 = nwg & 7;
  const int orig = blockIdx.x;
  const int xcd = orig & 7;
  const int wgid = (xcd < r8 ? xcd * (q8 + 1) : r8 * (q8 + 1) + (xcd - r8) * q8) + (orig >> 3);
  const int bx = wgid / NY;
  const int by = wgid - bx * NY;
  const int m0 = bx * 256;
  const int n0 = by * BN;

  constexpr int MREP = (BN == 256) ? 8 : 4;        // M-frags per wave
  constexpr int MPH  = MREP / 4;                    // M-frags per phase
  const int wm = (BN == 256) ? (wave >> 2) * 128 : (wave >> 1) * 64;
  const int wn = (BN == 256) ? (wave & 3) * 64 : (wave & 1) * 64;
  const int NS = K >> 6;                            // K-steps of 64

  float4v acc[MREP][4] = {};

  auto stageA = [&](int step, int half) {           // 16KB piece: A rows half*128..+128
    char* dst = lds + (step & 1) * BUFSZ + half * 16384;
    const int kb = step << 6;
    #pragma unroll
    for (int u = 0; u < 2; ++u) {
      int L = u * 8192 + tid * 16;
      int r = L >> 7, pc = (L >> 4) & 7, lc = pc ^ (r & 7);
      gload_lds16(A + (size_t)(m0 + half * 128 + r) * K + kb + lc * 8, dst + L);
    }
  };
  auto stageB = [&](int step, int half) {           // 16KB piece of B
    char* dst = lds + (step & 1) * BUFSZ + 32768 + half * 16384;
    const int kb = step << 6;
    #pragma unroll
    for (int u = 0; u < 2; ++u) {
      int L = u * 8192 + tid * 16;
      int r = L >> 7, pc = (L >> 4) & 7, lc = pc ^ (r & 7);
      gload_lds16(Bw + (size_t)(n0 + half * 128 + r) * K + kb + lc * 8, dst + L);
    }
  };

  // prologue: steps 0 and 1 fully staged
  stageA(0, 0); stageA(0, 1); stageB(0, 0); if (BN == 256) stageB(0, 1);
  stageA(1, 0); stageA(1, 1); stageB(1, 0); if (BN == 256) stageB(1, 1);
  if constexpr (BN == 256) asm volatile("s_waitcnt vmcnt(8)" ::: "memory");
  else                     asm volatile("s_waitcnt vmcnt(6)" ::: "memory");
  __builtin_amdgcn_s_barrier();

  short8v breg[4][2];
  const int NIT = NS >> 1;
  #pragma unroll 1
  for (int it = 0; it < NIT; ++it) {
    const int s = it * 2;
    #pragma unroll
    for (int half = 0; half < 2; ++half) {
      const int st = s + half;
      const char* bufA = lds + (st & 1) * BUFSZ;
      const char* bufB = bufA + 32768;
      #pragma unroll
      for (int q = 0; q < 4; ++q) {
        const int ph = half * 4 + q;
        // ---- ds_read: B (q0 only) + A quadrant ----
        if (q == 0) {
          #pragma unroll
          for (int j = 0; j < 4; ++j)
            #pragma unroll
            for (int ks = 0; ks < 2; ++ks) {
              int r = wn + j * 16 + (lane & 15);
              int c = ks * 4 + (lane >> 4);
              breg[j][ks] = *(const short8v*)(bufB + r * 128 + ((c ^ (r & 7)) << 4));
            }
        }
        short8v areg[MPH][2];
        #pragma unroll
        for (int f = 0; f < MPH; ++f)
          #pragma unroll
          for (int ks = 0; ks < 2; ++ks) {
            int r = wm + (q * MPH + f) * 16 + (lane & 15);
            int c = ks * 4 + (lane >> 4);
            areg[f][ks] = *(const short8v*)(bufA + r * 128 + ((c ^ (r & 7)) << 4));
          }
        // ---- stage one 16KB piece (schedule honors region-free constraints) ----
        if constexpr (BN == 256) {
          if (ph == 0)      { if (it > 0)      stageA(s + 1, 0); }
          else if (ph == 1) { if (it > 0)      stageA(s + 1, 1);
                              if (s + 2 < NS)  stageB(s + 2, 0); }
          else if (ph == 2) { if (s + 2 < NS)  stageB(s + 2, 1); }
          else if (ph == 4) { if (s + 2 < NS)  stageA(s + 2, 0); }
          else if (ph == 5) { if (s + 2 < NS)  stageA(s + 2, 1); }
          else if (ph == 6) { if (s + 3 < NS)  stageB(s + 3, 0); }
          else if (ph == 7) { if (s + 3 < NS)  stageB(s + 3, 1); }
        } else {
          if (ph == 0)      { if (it > 0)      stageA(s + 1, 0); }
          else if (ph == 1) { if (it > 0)      stageA(s + 1, 1);
                              if (s + 2 < NS)  stageB(s + 2, 0); }
          else if (ph == 4) { if (s + 2 < NS)  stageA(s + 2, 0); }
          else if (ph == 5) { if (s + 2 < NS)  stageA(s + 2, 1); }
          else if (ph == 6) { if (s + 3 < NS)  stageB(s + 3, 0); }
        }
        // ---- counted vmcnt, only at phase-group tails (never drains mid-loop) ----
        if (ph == 3) {
          if (s + 2 < NS) {
            if constexpr (BN == 256) asm volatile("s_waitcnt vmcnt(4)" ::: "memory");
            else                     asm volatile("s_waitcnt vmcnt(2)" ::: "memory");
          } else {
            asm volatile("s_waitcnt vmcnt(0)" ::: "memory");
          }
        } else if (ph == 7 && s + 2 < NS) {
          if constexpr (BN == 256) asm volatile("s_waitcnt vmcnt(4)" ::: "memory");
          else                     asm volatile("s_waitcnt vmcnt(2)" ::: "memory");
        }
        __builtin_amdgcn_s_barrier();
        asm volatile("s_waitcnt lgkmcnt(0)" ::: "memory");
        __builtin_amdgcn_sched_barrier(0);        // rule 18: pin MFMA below the wait
        __builtin_amdgcn_s_setprio(1);
        #pragma unroll
        for (int f = 0; f < MPH; ++f)
          #pragma unroll
          for (int j = 0; j < 4; ++j)
            #pragma unroll
            for (int ks = 0; ks < 2; ++ks)
              mfma16x16(acc[q * MPH + f][j], areg[f][ks], breg[j][ks]);
        __builtin_amdgcn_s_setprio(0);
        __builtin_amdgcn_s_barrier();
      }
    }
  }
  asm volatile("s_nop 7\n\ts_nop 7");              // MFMA->VALU hazard guard

  if (EPI == 0 || EPI == 2) {
    #pragma unroll
    for (int i = 0; i < MREP; ++i)
      #pragma unroll
      for (int j = 0; j < 4; ++j)
        #pragma unroll
        for (int r = 0; r < 4; ++r) {
          int m = m0 + wm + i * 16 + ((lane >> 4) << 2) + r;
          int n = n0 + wn + j * 16 + (lane & 15);
          float v = acc[i][j][r];
          if (EPI == 0) {
            outb[(size_t)m * N + n] = __float2bfloat16(v);
          } else {
            float z = v + bias[n];
            float g = 0.5f * z * (1.0f + erff(z * 0.70710678118654752f));
            outb[(size_t)m * N + n] = __float2bfloat16(g);
          }
        }
  } else if (EPI == 1) {
    #pragma unroll
    for (int i = 0; i < MREP; ++i)
      #pragma unroll
      for (int j = 0; j < 4; ++j)
        #pragma unroll
        for (int r = 0; r < 4; ++r) {
          int m = m0 + wm + i * 16 + ((lane >> 4) << 2) + r;
          int n = n0 + wn + j * 16 + (lane & 15);
          float v = acc[i][j][r] + bias[n];
          v = __bfloat162float(resid[(size_t)m * CCH + n]) + ls[n] * v;
          outb[(size_t)m * CCH + n] = __float2bfloat16(v);
        }
  } else {   // EPI == 3 : fused epilogue + in-LDS transpose -> NCHW fp32 (BN==128)
    float* LT = (float*)lds;                       // [64][260] fp32 = 66.5KB
    #pragma unroll 1
    for (int h = 0; h < 2; ++h) {
      __syncthreads();
      if ((wave & 1) == h) {
        #pragma unroll
        for (int i = 0; i < MREP; ++i)
          #pragma unroll
          for (int j = 0; j < 4; ++j)
            #pragma unroll
            for (int r = 0; r < 4; ++r) {
              int ml = wm + i * 16 + ((lane >> 4) << 2) + r;   // 0..255
              int nl = j * 16 + (lane & 15);                    // 0..63
              int ng = n0 + h * 64 + nl;
              float v = acc[i][j][r] + bias[ng];
              v = __bfloat162float(resid[(size_t)(m0 + ml) * CCH + ng]) + ls[ng] * v;
              LT[nl * 260 + ml] = v;
            }
      }
      __syncthreads();
      #pragma unroll 1
      for (int w = 0; w < 8; ++w) {
        int nl = (tid >> 6) + w * 8;               // 0..63
        int ng = n0 + h * 64 + nl;
        int ml = (lane) * 4;
        float4v v4 = *(const float4v*)(LT + nl * 260 + ml);
        int m = m0 + ml;
        int bb = m / NTOK, tt = m - bb * NTOK;
        if (tt <= NTOK - 4) {
          *(float4v*)(outf + (size_t)bb * (CCH * NTOK) + (size_t)ng * NTOK + tt) = v4;
        } else {
          #pragma unroll
          for (int e = 0; e < 4; ++e) {
            int m2 = m + e;
            int b2 = m2 / NTOK, t2 = m2 - b2 * NTOK;
            outf[(size_t)b2 * (CCH * NTOK) + (size_t)ng * NTOK + t2] = v4[e];
          }
        }
      }
    }
  }
}

// ---------------- attention: one block per (batch, head) ----------------

__global__ __launch_bounds__(256, 2) void attn_kernel(
    const __hip_bfloat16* __restrict__ qkv, __hip_bfloat16* __restrict__ o_t) {
  __shared__ char sQ[208 * 64];    // [208][32] bf16, chunk-swizzled rows
  __shared__ char sK[224 * 64];    // [224][32] bf16
  __shared__ char sV[32 * 448];    // V^T [32][224] bf16, chunk-swizzled
  __shared__ char sP[4][16 * 472]; // per-wave P [16][236] bf16
  const int tid  = threadIdx.x;
  const int lane = tid & 63;
  const int wave = tid >> 6;
  const int b = blockIdx.x >> 4;
  const int h = blockIdx.x & 15;
  const size_t qbase = (size_t)b * NTOK * 1536 + h * 32;

  {
    uint32_t* z = (uint32_t*)sQ;
    for (int i = tid; i < (208 * 64) / 4; i += 256) z[i] = 0u;
    z = (uint32_t*)sK;
    for (int i = tid; i < (224 * 64) / 4; i += 256) z[i] = 0u;
    z = (uint32_t*)sV;
    for (int i = tid; i < (32 * 448) / 4; i += 256) z[i] = 0u;
  }
  __syncthreads();

  for (int p = tid; p < NTOK * 4; p += 256) {
    int row = p >> 2, c = p & 3;
    const __hip_bfloat16* src = qkv + qbase + (size_t)row * 1536 + c * 8;
    short8v q = *(const short8v*)(src);
    short8v k = *(const short8v*)(src + 512);
    short8v v = *(const short8v*)(src + 1024);
    int pc = c ^ swz4(row);
    *(short8v*)(sQ + row * 64 + pc * 16) = q;
    *(short8v*)(sK + row * 64 + pc * 16) = k;
    #pragma unroll
    for (int j = 0; j < 8; ++j) {
      int d = c * 8 + j;
      int ch = (row >> 3) ^ swz4(d);
      *(uint16_t*)(sV + d * 448 + ch * 16 + (row & 7) * 2) = (uint16_t)v[j];
    }
  }
  __syncthreads();

  const float scale = 0.17677669529663687f;   // 1/sqrt(32)
  char* Pw = sP[wave];

  for (int mt = wave; mt < 13; mt += 4) {
    int qrow = mt * 16 + (lane & 15);
    int pcq = (lane >> 4) ^ swz4(qrow);
    short8v aq = *(const short8v*)(sQ + qrow * 64 + pcq * 16);

    float4v s[14];
    #pragma unroll
    for (int nt = 0; nt < 14; ++nt) {
      int krow = nt * 16 + (lane & 15);
      int pck = (lane >> 4) ^ swz4(krow);
      short8v bk = *(const short8v*)(sK + krow * 64 + pck * 16);
      s[nt] = float4v{0.f, 0.f, 0.f, 0.f};
      mfma16x16(s[nt], aq, bk);
    }
    asm volatile("s_nop 7\n\ts_nop 7");

    float mx[4] = {-INFINITY, -INFINITY, -INFINITY, -INFINITY};
    #pragma unroll
    for (int nt = 0; nt < 14; ++nt) {
      bool valid = (nt * 16 + (lane & 15)) < NTOK;
      #pragma unroll
      for (int r = 0; r < 4; ++r) {
        float v = valid ? s[nt][r] * scale : -INFINITY;
        s[nt][r] = v;
        mx[r] = fmaxf(mx[r], v);
      }
    }
    #pragma unroll
    for (int off = 1; off < 16; off <<= 1) {
      #pragma unroll
      for (int r = 0; r < 4; ++r) mx[r] = fmaxf(mx[r], __shfl_xor(mx[r], off));
    }
    float sum[4] = {0.f, 0.f, 0.f, 0.f};
    #pragma unroll
    for (int nt = 0; nt < 14; ++nt) {
      #pragma unroll
      for (int r = 0; r < 4; ++r) {
        float e = __expf(s[nt][r] - mx[r]);
        s[nt][r] = e;
        sum[r] += e;
      }
    }
    #pragma unroll
    for (int off = 1; off < 16; off <<= 1) {
      #pragma unroll
      for (int r = 0; r < 4; ++r) sum[r] += __shfl_xor(sum[r], off);
    }
    float rs[4];
    #pragma unroll
    for (int r = 0; r < 4; ++r) rs[r] = 1.0f / sum[r];

    #pragma unroll
    for (int nt = 0; nt < 14; ++nt) {
      int col = nt * 16 + (lane & 15);
      #pragma unroll
      for (int r = 0; r < 4; ++r) {
        int prow = ((lane >> 4) << 2) + r;
        *(__hip_bfloat16*)(Pw + prow * 472 + col * 2) = __float2bfloat16(s[nt][r] * rs[r]);
      }
    }

    float4v o0 = float4v{0.f, 0.f, 0.f, 0.f};
    float4v o1 = float4v{0.f, 0.f, 0.f, 0.f};
    #pragma unroll
    for (int ks = 0; ks < 7; ++ks) {
      short8v pa = *(const short8v*)(Pw + (lane & 15) * 472 + ks * 64 + ((lane >> 4) << 4));
      int kc = ks * 4 + (lane >> 4);
      int d0 = (lane & 15);
      int d1 = 16 + (lane & 15);
      short8v v0 = *(const short8v*)(sV + d0 * 448 + ((kc ^ swz4(d0)) << 4));
      short8v v1 = *(const short8v*)(sV + d1 * 448 + ((kc ^ swz4(d1)) << 4));
      mfma16x16(o0, pa, v0);
      mfma16x16(o1, pa, v1);
    }
    asm volatile("s_nop 7\n\ts_nop 7");

    #pragma unroll
    for (int r = 0; r < 4; ++r) {
      int trow = mt * 16 + ((lane >> 4) << 2) + r;
      if (trow < NTOK) {
        size_t ob = ((size_t)b * NTOK + trow) * CCH + h * 32 + (lane & 15);
        o_t[ob] = __float2bfloat16(o0[r]);
        o_t[ob + 16] = __float2bfloat16(o1[r]);
      }
    }
  }
}

// ---------------- depthwise 7x7 conv, token-major (+BN in, +fBN out) ----------------

__global__ __launch_bounds__(448) void dwconv_tm(
    const __hip_bfloat16* __restrict__ x1t, const float* __restrict__ dw_w,
    const float* __restrict__ cst, __hip_bfloat16* __restrict__ yt) {
  __shared__ float img[196][32];
  __shared__ float wgt[49][32];
  const int tid = threadIdx.x;
  const int b  = blockIdx.x >> 4;
  const int cb = (blockIdx.x & 15) * 32;
  const int c  = tid & 31;
  const int gc = cb + c;
  const float s = cst[gc], t0 = cst[512 + gc];
  #pragma unroll
  for (int k = 0; k < 14; ++k) {
    int p = (tid >> 5) + k * 14;
    img[p][c] = __bfloat162float(x1t[((size_t)b * NTOK + p) * CCH + gc]) * s + t0;
  }
  for (int i = tid; i < 49 * 32; i += 448) {
    int tap = i >> 5, cc = i & 31;
    wgt[tap][cc] = dw_w[(cb + cc) * 49 + tap];
  }
  __syncthreads();

  const int px = tid >> 5;        // 0..13
  float out[14];
  #pragma unroll
  for (int i = 0; i < 14; ++i) out[i] = 0.f;
  #pragma unroll 1
  for (int row = 0; row < 14; ++row) {
    float v[7];
    #pragma unroll
    for (int dx = 0; dx < 7; ++dx) {
      int ix = px + dx - 3;
      v[dx] = ((unsigned)ix < 14u) ? img[row * 14 + ix][c] : 0.f;
    }
    #pragma unroll
    for (int kk = 0; kk < 7; ++kk) {
      int py = row + 3 - kk;
      if (py >= 0 && py < 14) {
        float hsum = 0.f;
        #pragma unroll
        for (int dx = 0; dx < 7; ++dx) hsum = fmaf(v[dx], wgt[kk * 7 + dx][c], hsum);
        out[py] += hsum;
      }
    }
  }
  const float fs = cst[1024 + gc], ft = cst[1536 + gc];
  #pragma unroll
  for (int py = 0; py < 14; ++py)
    yt[((size_t)b * NTOK + py * 14 + px) * CCH + gc] = __float2bfloat16(out[py] * fs + ft);
}

// ---------------- launch ----------------

extern "C" void kernel_launch(void* const* d_in, const int* in_sizes, int n_in,
                              void* d_out, int out_size, void* d_ws, size_t ws_size,
                              hipStream_t stream) {
  const float* x      = (const float*)d_in[0];
  const float* bn_g   = (const float*)d_in[1];
  const float* bn_b   = (const float*)d_in[2];
  const float* bn_m   = (const float*)d_in[3];
  const float* bn_v   = (const float*)d_in[4];
  const float* qkv_w  = (const float*)d_in[5];
  const float* proj_w = (const float*)d_in[6];
  const float* proj_b = (const float*)d_in[7];
  const float* dw_w   = (const float*)d_in[8];
  const float* fbn_g  = (const float*)d_in[9];
  const float* fbn_b  = (const float*)d_in[10];
  const float* fbn_m  = (const float*)d_in[11];
  const float* fbn_v  = (const float*)d_in[12];
  const float* fc1_w  = (const float*)d_in[13];
  const float* fc1_b  = (const float*)d_in[14];
  const float* fc2_w  = (const float*)d_in[15];
  const float* fc2_b  = (const float*)d_in[16];
  const float* ls1    = (const float*)d_in[17];
  const float* ls2    = (const float*)d_in[18];

  char* ws = (char*)d_ws;
  float* cst             = (float*)ws;                       // 8 KB
  __hip_bfloat16* qkvb   = (__hip_bfloat16*)(ws + 8192);
  __hip_bfloat16* projb  = (__hip_bfloat16*)(ws + 1581056);
  __hip_bfloat16* fc1b   = (__hip_bfloat16*)(ws + 2105344);
  __hip_bfloat16* fc2b   = (__hip_bfloat16*)(ws + 4202496);
  __hip_bfloat16* xnt    = (__hip_bfloat16*)(ws + 6299648);   // 12.85 MB
  __hip_bfloat16* xt     = (__hip_bfloat16*)(ws + 19144704);  // 12.85 MB
  __hip_bfloat16* qkvt   = (__hip_bfloat16*)(ws + 31989760);  // 38.5 MB
  __hip_bfloat16* ot     = (__hip_bfloat16*)(ws + 70524928);  // 12.85 MB
  __hip_bfloat16* x1t    = (__hip_bfloat16*)(ws + 83369984);  // 12.85 MB
  __hip_bfloat16* yt     = (__hip_bfloat16*)(ws + 96215040);  // 12.85 MB (end 109060096)
  __hip_bfloat16* hbuf   = (__hip_bfloat16*)(ws + 6299648);   // 51.4 MB overlay (xnt/xt/qkvt dead)

  prep_consts<<<dim3(2), dim3(256), 0, stream>>>(bn_g, bn_b, bn_m, bn_v,
                                                 fbn_g, fbn_b, fbn_m, fbn_v, cst);
  cvt_weights<<<dim3(3072), dim3(256), 0, stream>>>(qkv_w, proj_w, fc1_w, fc2_w,
                                                    qkvb, projb, fc1b, fc2b);
  transpose_x<<<dim3(7, 16, 64), dim3(256), 0, stream>>>(x, xnt, xt, cst);
  // QKV: M=12544, N=1536, K=512 ; 256x256 -> 49*6 = 294 blocks
  gemm8p<256, 0><<<dim3(294), dim3(512), 0, stream>>>(xnt, qkvb, 1536, 512, 6,
                                                      qkvt, nullptr, nullptr, nullptr, nullptr);
  attn_kernel<<<dim3(1024), dim3(256), 0, stream>>>(qkvt, ot);
  // proj: N=512, K=512 ; 256x128 -> 49*4 = 196 blocks
  gemm8p<128, 1><<<dim3(196), dim3(512), 0, stream>>>(ot, projb, 512, 512, 4,
                                                      x1t, nullptr, proj_b, ls1, xt);
  dwconv_tm<<<dim3(1024), dim3(448), 0, stream>>>(x1t, dw_w, cst, yt);
  // fc1: N=2048, K=512 ; 256x256 -> 49*8 = 392 blocks
  gemm8p<256, 2><<<dim3(392), dim3(512), 0, stream>>>(yt, fc1b, 2048, 512, 8,
                                                      hbuf, nullptr, fc1_b, nullptr, nullptr);
  // fc2: N=512, K=2048 ; 256x128 -> 196 blocks ; NCHW fp32 out
  gemm8p<128, 3><<<dim3(196), dim3(512), 0, stream>>>(hbuf, fc2b, 512, 2048, 4,
                                                      nullptr, (float*)d_out, fc2_b, ls2, x1t);
}

// Round 12
// 218.711 us; speedup vs baseline: 1.5255x; 1.2735x over previous
//
#include <hip/hip_runtime.h>
#include <hip/hip_bf16.h>
#include <hip/hip_fp8.h>
#include <stdint.h>

#define NTOK 196
#define NB   64
#define CCH  512
#define HID  2048
#define MTOT (NB * NTOK)   // 12544

typedef __attribute__((ext_vector_type(8))) short  short8v;
typedef __attribute__((ext_vector_type(4))) float  float4v;
typedef __attribute__((ext_vector_type(2))) int    int2v;

// ---------------- helpers ----------------

__device__ __forceinline__ void mfma16x16(float4v& d, short8v a, short8v b) {
  asm("v_mfma_f32_16x16x32_bf16 %0, %1, %2, %0" : "+v"(d) : "v"(a), "v"(b));
}

__device__ __forceinline__ void mfma_fp8(float4v& d, int2v a, int2v b) {
  asm("v_mfma_f32_16x16x32_fp8_fp8 %0, %1, %2, %0" : "+v"(d) : "v"(a), "v"(b));
}

__device__ __forceinline__ void gload_lds16(const void* gsrc, void* ldst) {
  __builtin_amdgcn_global_load_lds(
      (const __attribute__((address_space(1))) unsigned int*)gsrc,
      (__attribute__((address_space(3))) unsigned int*)ldst, 16, 0, 0);
}

__device__ __forceinline__ int swz4(int r) { return (r ^ (r >> 2)) & 3; }

__device__ __forceinline__ uint8_t to_fp8(float v) {
  return __hip_fp8_e4m3(v).__x;
}

// ---------------- prep: BN constants ----------------

__global__ void prep_consts(const float* __restrict__ bn_g, const float* __restrict__ bn_b,
                            const float* __restrict__ bn_m, const float* __restrict__ bn_v,
                            const float* __restrict__ fbn_g, const float* __restrict__ fbn_b,
                            const float* __restrict__ fbn_m, const float* __restrict__ fbn_v,
                            float* __restrict__ cst) {
  int c = blockIdx.x * blockDim.x + threadIdx.x;
  if (c < CCH) {
    float i1 = bn_g[c] * rsqrtf(bn_v[c] + 1e-5f);
    cst[c] = i1;
    cst[512 + c] = bn_b[c] - bn_m[c] * i1;
    float i2 = fbn_g[c] * rsqrtf(fbn_v[c] + 1e-5f);
    cst[1024 + c] = i2;
    cst[1536 + c] = fbn_b[c] - fbn_m[c] * i2;
  }
}

// ---------------- weights fp32 -> fp8 e4m3, x16 ----------------

__global__ void cvt_weights(const float* __restrict__ qkv_w, const float* __restrict__ proj_w,
                            const float* __restrict__ fc1_w, const float* __restrict__ fc2_w,
                            uint8_t* __restrict__ qkvb, uint8_t* __restrict__ projb,
                            uint8_t* __restrict__ fc1b, uint8_t* __restrict__ fc2b) {
  int i4 = blockIdx.x * blockDim.x + threadIdx.x;    // unit = 4 floats
  const int nq = 1536 * 512 / 4;
  const int np = 512 * 512 / 4;
  const int n1 = 2048 * 512 / 4;
  const float* src;
  uint8_t* dst;
  int k;
  if (i4 < nq)                { src = qkv_w;  dst = qkvb;  k = i4; }
  else if (i4 < nq + np)      { src = proj_w; dst = projb; k = i4 - nq; }
  else if (i4 < nq + np + n1) { src = fc1_w;  dst = fc1b;  k = i4 - nq - np; }
  else                        { src = fc2_w;  dst = fc2b;  k = i4 - nq - np - n1; }
  float4v v = *(const float4v*)(src + 4 * (size_t)k);
  #pragma unroll
  for (int l = 0; l < 4; ++l) dst[4 * (size_t)k + l] = to_fp8(v[l] * 16.0f);
}

// ---------------- transpose NCHW fp32 -> token-major: fp8 (BN'd) + bf16 (raw) ----------------

__global__ __launch_bounds__(256) void transpose_x(
    const float* __restrict__ x, uint8_t* __restrict__ xnt8,
    __hip_bfloat16* __restrict__ xt, const float* __restrict__ cst) {
  __shared__ float tile[32][33];
  const int n0 = blockIdx.x * 32;
  const int c0 = blockIdx.y * 32;
  const int b  = blockIdx.z;
  const int j = threadIdx.x & 31, i = threadIdx.x >> 5;
  #pragma unroll
  for (int p = 0; p < 4; ++p) {
    int cc = c0 + i + p * 8;
    int n = n0 + j;
    if (n < NTOK) tile[i + p * 8][j] = x[((size_t)b * CCH + cc) * NTOK + n];
  }
  __syncthreads();
  const float s = cst[c0 + j], t = cst[512 + c0 + j];
  #pragma unroll
  for (int p = 0; p < 4; ++p) {
    int n = n0 + i + p * 8;
    int cc = c0 + j;
    if (n < NTOK) {
      float raw = tile[j][i + p * 8];
      size_t o = ((size_t)b * NTOK + n) * CCH + cc;
      xt[o]   = __float2bfloat16(raw);
      xnt8[o] = to_fp8(raw * s + t);
    }
  }
}

// ---------------- fp8 GEMM, R2 schedule: C[M,N] = (A[M,K]*B[N,K]^T)/16 ----------------
// Triple-buffered, counted-vmcnt pipeline, raw s_barrier — byte-for-byte R2 structure.
// LDS buf = A 8KB + B 8KB (128 rows x 64 fp8 = two K=32 subtiles), 16B-chunk XOR swizzle.
// Operands: ds_read_b64 (2 VGPR), v_mfma_f32_16x16x32_fp8_fp8.
// EPI: 0 = qkv: bf16(v/16)            1 = proj: x1t = xt + ls1*(v/16+bias)
//      2 = fc1: gelu(v/16+bias)->fp8  3 = fc2: out = x1t + ls2*(v/16+bias) -> NCHW fp32

template<int EPI>
__global__ __launch_bounds__(256, 3) void gemm8f(
    const uint8_t* __restrict__ A, const uint8_t* __restrict__ Bw,
    int N, int K, int NY,
    __hip_bfloat16* __restrict__ outb, uint8_t* __restrict__ out8,
    float* __restrict__ outf,
    const float* __restrict__ bias, const float* __restrict__ ls,
    const __hip_bfloat16* __restrict__ resid) {
  __shared__ char lds[49152];   // 3 bufs x (A 8KB + B 8KB)
  const int tid  = threadIdx.x;
  const int lane = tid & 63;
  const int wave = tid >> 6;

  // bijective XCD swizzle (nwg % 8 == 0 for all our grids), by-fast linearization
  const int q    = (int)gridDim.x >> 3;
  const int orig = blockIdx.x;
  const int wgid = (orig & 7) * q + (orig >> 3);
  const int bx = wgid / NY;
  const int by = wgid - bx * NY;

  const int m0 = bx * 128;
  const int n0 = by * 128;
  const int wm = (wave >> 1) * 64;
  const int wn = (wave & 1) * 64;
  const int KT = K >> 6;                 // 64-deep K chunks

  float4v acc[4][4] = {};

  auto stage = [&](int buf, int kt) {
    const int kb = kt * 64;
    char* base = lds + buf * 16384;
    #pragma unroll
    for (int i = 0; i < 2; ++i) {
      int L = i * 4096 + tid * 16;
      int row = L >> 6;
      int lc = ((L >> 4) & 3) ^ swz4(row);
      gload_lds16(A + (size_t)(m0 + row) * K + kb + lc * 16, base + L);
    }
    #pragma unroll
    for (int i = 0; i < 2; ++i) {
      int L = i * 4096 + tid * 16;
      int row = L >> 6;
      int lc = ((L >> 4) & 3) ^ swz4(row);
      gload_lds16(Bw + (size_t)(n0 + row) * K + kb + lc * 16, base + 8192 + L);
    }
  };

  auto compute = [&](int buf) {
    const char* bA = lds + buf * 16384;
    const char* bB = bA + 8192;
    const int g = lane >> 4;
    #pragma unroll
    for (int t = 0; t < 2; ++t) {        // two K=32 subtiles per buf
      int2v av[4], bv[4];
      #pragma unroll
      for (int f = 0; f < 4; ++f) {
        int row = wm + f * 16 + (lane & 15);
        int c16 = ((t << 1) | (g >> 1)) ^ swz4(row);
        av[f] = *(const int2v*)(bA + row * 64 + c16 * 16 + (g & 1) * 8);
      }
      #pragma unroll
      for (int j = 0; j < 4; ++j) {
        int row = wn + j * 16 + (lane & 15);
        int c16 = ((t << 1) | (g >> 1)) ^ swz4(row);
        bv[j] = *(const int2v*)(bB + row * 64 + c16 * 16 + (g & 1) * 8);
      }
      #pragma unroll
      for (int i = 0; i < 4; ++i)
        #pragma unroll
        for (int j = 0; j < 4; ++j)
          mfma_fp8(acc[i][j], av[i], bv[j]);
    }
  };

  // prologue: 2 bufs in flight (8 gload_lds per thread)
  stage(0, 0);
  stage(1, 1);
  int cur = 0;
  for (int kt = 0; kt < KT - 1; ++kt) {
    asm volatile("s_waitcnt vmcnt(4)" ::: "memory");   // oldest stage complete
    __builtin_amdgcn_s_barrier();
    __builtin_amdgcn_sched_barrier(0);
    if (kt + 2 < KT) {
      int s = cur + 2; if (s >= 3) s -= 3;
      stage(s, kt + 2);
    }
    compute(cur);
    ++cur; if (cur == 3) cur = 0;
  }
  asm volatile("s_waitcnt vmcnt(0)" ::: "memory");
  __builtin_amdgcn_s_barrier();
  __builtin_amdgcn_sched_barrier(0);
  compute(cur);
  asm volatile("s_nop 7\n\ts_nop 7");      // MFMA->VALU hazard guard

  const float RS = 0.0625f;                // undo weight x16

  if (EPI == 0 || EPI == 2) {
    #pragma unroll
    for (int i = 0; i < 4; ++i)
      #pragma unroll
      for (int j = 0; j < 4; ++j)
        #pragma unroll
        for (int r = 0; r < 4; ++r) {
          int m = m0 + wm + i * 16 + ((lane >> 4) << 2) + r;
          int n = n0 + wn + j * 16 + (lane & 15);
          float v = acc[i][j][r] * RS;
          if (EPI == 0) {
            outb[(size_t)m * N + n] = __float2bfloat16(v);
          } else {
            float z = v + bias[n];
            float g2 = z / (1.0f + __expf(-1.702f * z));  // fast GELU (x1e-5 after ls2)
            out8[(size_t)m * N + n] = to_fp8(g2);
          }
        }
  } else if (EPI == 1) {
    #pragma unroll
    for (int i = 0; i < 4; ++i)
      #pragma unroll
      for (int j = 0; j < 4; ++j)
        #pragma unroll
        for (int r = 0; r < 4; ++r) {
          int m = m0 + wm + i * 16 + ((lane >> 4) << 2) + r;
          int n = n0 + wn + j * 16 + (lane & 15);
          float v = acc[i][j][r] * RS + bias[n];
          v = __bfloat162float(resid[(size_t)m * CCH + n]) + ls[n] * v;
          outb[(size_t)m * CCH + n] = __float2bfloat16(v);
        }
  } else {   // EPI == 3 : fused epilogue + in-LDS transpose -> NCHW fp32
    float* LT = (float*)lds;   // [64][129] fp32 = 33KB
    #pragma unroll 1
    for (int hh = 0; hh < 2; ++hh) {
      __syncthreads();
      if ((wn >> 6) == hh) {
        #pragma unroll
        for (int i = 0; i < 4; ++i)
          #pragma unroll
          for (int j = 0; j < 4; ++j)
            #pragma unroll
            for (int r = 0; r < 4; ++r) {
              int ml = wm + i * 16 + ((lane >> 4) << 2) + r;
              int nl = j * 16 + (lane & 15);
              int n = n0 + wn + nl;
              float v = acc[i][j][r] * RS + bias[n];
              v = __bfloat162float(resid[(size_t)(m0 + ml) * CCH + n]) + ls[n] * v;
              LT[nl * 129 + ml] = v;
            }
      }
      __syncthreads();
      {
        int ml0 = lane << 1;
        int mg = m0 + ml0;
        int bb0 = mg / NTOK;
        int tt0 = mg - bb0 * NTOK;
        int bb1 = (mg + 1) / NTOK;
        int tt1 = (mg + 1) - bb1 * NTOK;
        size_t base0 = (size_t)bb0 * (CCH * NTOK) + tt0;
        size_t base1 = (size_t)bb1 * (CCH * NTOK) + tt1;
        #pragma unroll
        for (int u = 0; u < 16; ++u) {
          int cr = wave * 16 + u;
          int cg = n0 + hh * 64 + cr;
          float v0 = LT[cr * 129 + ml0];
          float v1 = LT[cr * 129 + ml0 + 1];
          outf[base0 + (size_t)cg * NTOK] = v0;
          outf[base1 + (size_t)cg * NTOK] = v1;
        }
      }
    }
  }
}

// ---------------- attention: one block per (batch, head), bf16 compute, fp8 out ----------------

__global__ __launch_bounds__(256, 2) void attn_kernel(
    const __hip_bfloat16* __restrict__ qkv, uint8_t* __restrict__ o_t8) {
  __shared__ char sQ[208 * 64];    // [208][32] bf16, chunk-swizzled rows
  __shared__ char sK[224 * 64];    // [224][32] bf16
  __shared__ char sV[32 * 448];    // V^T [32][224] bf16, chunk-swizzled
  __shared__ char sP[4][16 * 472]; // per-wave P [16][236] bf16
  const int tid  = threadIdx.x;
  const int lane = tid & 63;
  const int wave = tid >> 6;
  const int b = blockIdx.x >> 4;
  const int h = blockIdx.x & 15;
  const size_t qbase = (size_t)b * NTOK * 1536 + h * 32;

  {
    uint32_t* z = (uint32_t*)sQ;
    for (int i = tid; i < (208 * 64) / 4; i += 256) z[i] = 0u;
    z = (uint32_t*)sK;
    for (int i = tid; i < (224 * 64) / 4; i += 256) z[i] = 0u;
    z = (uint32_t*)sV;
    for (int i = tid; i < (32 * 448) / 4; i += 256) z[i] = 0u;
  }
  __syncthreads();

  for (int p = tid; p < NTOK * 4; p += 256) {
    int row = p >> 2, c = p & 3;
    const __hip_bfloat16* src = qkv + qbase + (size_t)row * 1536 + c * 8;
    short8v q = *(const short8v*)(src);
    short8v k = *(const short8v*)(src + 512);
    short8v v = *(const short8v*)(src + 1024);
    int pc = c ^ swz4(row);
    *(short8v*)(sQ + row * 64 + pc * 16) = q;
    *(short8v*)(sK + row * 64 + pc * 16) = k;
    #pragma unroll
    for (int j = 0; j < 8; ++j) {
      int d = c * 8 + j;
      int ch = (row >> 3) ^ swz4(d);
      *(uint16_t*)(sV + d * 448 + ch * 16 + (row & 7) * 2) = (uint16_t)v[j];
    }
  }
  __syncthreads();

  const float scale = 0.17677669529663687f;   // 1/sqrt(32)
  char* Pw = sP[wave];

  for (int mt = wave; mt < 13; mt += 4) {
    int qrow = mt * 16 + (lane & 15);
    int pcq = (lane >> 4) ^ swz4(qrow);
    short8v aq = *(const short8v*)(sQ + qrow * 64 + pcq * 16);

    float4v s[14];
    #pragma unroll
    for (int nt = 0; nt < 14; ++nt) {
      int krow = nt * 16 + (lane & 15);
      int pck = (lane >> 4) ^ swz4(krow);
      short8v bk = *(const short8v*)(sK + krow * 64 + pck * 16);
      s[nt] = float4v{0.f, 0.f, 0.f, 0.f};
      mfma16x16(s[nt], aq, bk);
    }
    asm volatile("s_nop 7\n\ts_nop 7");

    float mx[4] = {-INFINITY, -INFINITY, -INFINITY, -INFINITY};
    #pragma unroll
    for (int nt = 0; nt < 14; ++nt) {
      bool valid = (nt * 16 + (lane & 15)) < NTOK;
      #pragma unroll
      for (int r = 0; r < 4; ++r) {
        float v = valid ? s[nt][r] * scale : -INFINITY;
        s[nt][r] = v;
        mx[r] = fmaxf(mx[r], v);
      }
    }
    #pragma unroll
    for (int off = 1; off < 16; off <<= 1) {
      #pragma unroll
      for (int r = 0; r < 4; ++r) mx[r] = fmaxf(mx[r], __shfl_xor(mx[r], off));
    }
    float sum[4] = {0.f, 0.f, 0.f, 0.f};
    #pragma unroll
    for (int nt = 0; nt < 14; ++nt) {
      #pragma unroll
      for (int r = 0; r < 4; ++r) {
        float e = __expf(s[nt][r] - mx[r]);
        s[nt][r] = e;
        sum[r] += e;
      }
    }
    #pragma unroll
    for (int off = 1; off < 16; off <<= 1) {
      #pragma unroll
      for (int r = 0; r < 4; ++r) sum[r] += __shfl_xor(sum[r], off);
    }
    float rs[4];
    #pragma unroll
    for (int r = 0; r < 4; ++r) rs[r] = 1.0f / sum[r];

    #pragma unroll
    for (int nt = 0; nt < 14; ++nt) {
      int col = nt * 16 + (lane & 15);
      #pragma unroll
      for (int r = 0; r < 4; ++r) {
        int prow = ((lane >> 4) << 2) + r;
        *(__hip_bfloat16*)(Pw + prow * 472 + col * 2) = __float2bfloat16(s[nt][r] * rs[r]);
      }
    }

    float4v o0 = float4v{0.f, 0.f, 0.f, 0.f};
    float4v o1 = float4v{0.f, 0.f, 0.f, 0.f};
    #pragma unroll
    for (int ks = 0; ks < 7; ++ks) {
      short8v pa = *(const short8v*)(Pw + (lane & 15) * 472 + ks * 64 + ((lane >> 4) << 4));
      int kc = ks * 4 + (lane >> 4);
      int d0 = (lane & 15);
      int d1 = 16 + (lane & 15);
      short8v v0 = *(const short8v*)(sV + d0 * 448 + ((kc ^ swz4(d0)) << 4));
      short8v v1 = *(const short8v*)(sV + d1 * 448 + ((kc ^ swz4(d1)) << 4));
      mfma16x16(o0, pa, v0);
      mfma16x16(o1, pa, v1);
    }
    asm volatile("s_nop 7\n\ts_nop 7");

    #pragma unroll
    for (int r = 0; r < 4; ++r) {
      int trow = mt * 16 + ((lane >> 4) << 2) + r;
      if (trow < NTOK) {
        size_t ob = ((size_t)b * NTOK + trow) * CCH + h * 32 + (lane & 15);
        o_t8[ob] = to_fp8(o0[r]);
        o_t8[ob + 16] = to_fp8(o1[r]);
      }
    }
  }
}

// ---------------- depthwise 7x7 conv, token-major (+BN in, +fBN out, fp8 out) ----------------

__global__ __launch_bounds__(448) void dwconv_tm(
    const __hip_bfloat16* __restrict__ x1t, const float* __restrict__ dw_w,
    const float* __restrict__ cst, uint8_t* __restrict__ yt8) {
  __shared__ float img[196][32];
  __shared__ float wgt[49][32];
  const int tid = threadIdx.x;
  const int b  = blockIdx.x >> 4;
  const int cb = (blockIdx.x & 15) * 32;
  const int c  = tid & 31;
  const int gc = cb + c;
  const float s = cst[gc], t0 = cst[512 + gc];
  #pragma unroll
  for (int k = 0; k < 14; ++k) {
    int p = (tid >> 5) + k * 14;
    img[p][c] = __bfloat162float(x1t[((size_t)b * NTOK + p) * CCH + gc]) * s + t0;
  }
  for (int i = tid; i < 49 * 32; i += 448) {
    int tap = i >> 5, cc = i & 31;
    wgt[tap][cc] = dw_w[(cb + cc) * 49 + tap];
  }
  __syncthreads();

  const int px = tid >> 5;        // 0..13
  float out[14];
  #pragma unroll
  for (int i = 0; i < 14; ++i) out[i] = 0.f;
  #pragma unroll 1
  for (int row = 0; row < 14; ++row) {
    float v[7];
    #pragma unroll
    for (int dx = 0; dx < 7; ++dx) {
      int ix = px + dx - 3;
      v[dx] = ((unsigned)ix < 14u) ? img[row * 14 + ix][c] : 0.f;
    }
    #pragma unroll
    for (int kk = 0; kk < 7; ++kk) {
      int py = row + 3 - kk;
      if (py >= 0 && py < 14) {
        float hsum = 0.f;
        #pragma unroll
        for (int dx = 0; dx < 7; ++dx) hsum = fmaf(v[dx], wgt[kk * 7 + dx][c], hsum);
        out[py] += hsum;
      }
    }
  }
  const float fs = cst[1024 + gc], ft = cst[1536 + gc];
  #pragma unroll
  for (int py = 0; py < 14; ++py)
    yt8[((size_t)b * NTOK + py * 14 + px) * CCH + gc] = to_fp8(out[py] * fs + ft);
}

// ---------------- launch ----------------

extern "C" void kernel_launch(void* const* d_in, const int* in_sizes, int n_in,
                              void* d_out, int out_size, void* d_ws, size_t ws_size,
                              hipStream_t stream) {
  const float* x      = (const float*)d_in[0];
  const float* bn_g   = (const float*)d_in[1];
  const float* bn_b   = (const float*)d_in[2];
  const float* bn_m   = (const float*)d_in[3];
  const float* bn_v   = (const float*)d_in[4];
  const float* qkv_w  = (const float*)d_in[5];
  const float* proj_w = (const float*)d_in[6];
  const float* proj_b = (const float*)d_in[7];
  const float* dw_w   = (const float*)d_in[8];
  const float* fbn_g  = (const float*)d_in[9];
  const float* fbn_b  = (const float*)d_in[10];
  const float* fbn_m  = (const float*)d_in[11];
  const float* fbn_v  = (const float*)d_in[12];
  const float* fc1_w  = (const float*)d_in[13];
  const float* fc1_b  = (const float*)d_in[14];
  const float* fc2_w  = (const float*)d_in[15];
  const float* fc2_b  = (const float*)d_in[16];
  const float* ls1    = (const float*)d_in[17];
  const float* ls2    = (const float*)d_in[18];

  char* ws = (char*)d_ws;
  float* cst             = (float*)ws;                        // 8 KB
  uint8_t* qkvb8         = (uint8_t*)(ws + 32768);            // 768 KB
  uint8_t* projb8        = (uint8_t*)(ws + 819200);           // 256 KB
  uint8_t* fc1b8         = (uint8_t*)(ws + 1081344);          // 1 MB
  uint8_t* fc2b8         = (uint8_t*)(ws + 2129920);          // 1 MB
  uint8_t* xnt8          = (uint8_t*)(ws + 3178496);          // 6.4 MB (fp8 BN'd x)
  __hip_bfloat16* xt     = (__hip_bfloat16*)(ws + 9601024);   // 12.85 MB (raw x, resid)
  __hip_bfloat16* qkvt   = (__hip_bfloat16*)(ws + 22446080);  // 38.5 MB
  uint8_t* ot8           = (uint8_t*)(ws + 60981248);         // 6.4 MB
  __hip_bfloat16* x1t    = (__hip_bfloat16*)(ws + 67403776);  // 12.85 MB
  uint8_t* yt8           = (uint8_t*)(ws + 80248832);         // 6.4 MB (end 86.7 MB)
  uint8_t* h8            = (uint8_t*)(ws + 3178496);          // 25.7 MB overlay (xnt8/xt/qkvt dead)

  prep_consts<<<dim3(2), dim3(256), 0, stream>>>(bn_g, bn_b, bn_m, bn_v,
                                                 fbn_g, fbn_b, fbn_m, fbn_v, cst);
  cvt_weights<<<dim3(3072), dim3(256), 0, stream>>>(qkv_w, proj_w, fc1_w, fc2_w,
                                                    qkvb8, projb8, fc1b8, fc2b8);
  transpose_x<<<dim3(7, 16, 64), dim3(256), 0, stream>>>(x, xnt8, xt, cst);
  // QKV: M=12544, N=1536, K=512 ; 128x128 -> 98*12 = 1176 blocks
  gemm8f<0><<<dim3(1176), dim3(256), 0, stream>>>(xnt8, qkvb8, 1536, 512, 12,
                                                  qkvt, nullptr, nullptr, nullptr, nullptr, nullptr);
  attn_kernel<<<dim3(1024), dim3(256), 0, stream>>>(qkvt, ot8);
  // proj: N=512, K=512 ; 98*4 = 392 blocks
  gemm8f<1><<<dim3(392), dim3(256), 0, stream>>>(ot8, projb8, 512, 512, 4,
                                                 x1t, nullptr, nullptr, proj_b, ls1, xt);
  dwconv_tm<<<dim3(1024), dim3(448), 0, stream>>>(x1t, dw_w, cst, yt8);
  // fc1: N=2048, K=512 ; 98*16 = 1568 blocks
  gemm8f<2><<<dim3(1568), dim3(256), 0, stream>>>(yt8, fc1b8, 2048, 512, 16,
                                                  nullptr, h8, nullptr, fc1_b, nullptr, nullptr);
  // fc2: N=512, K=2048 ; 392 blocks ; NCHW fp32 out
  gemm8f<3><<<dim3(392), dim3(256), 0, stream>>>(h8, fc2b8, 512, 2048, 4,
                                                 nullptr, nullptr, (float*)d_out, fc2_b, ls2, x1t);
}

// Round 13
// 205.589 us; speedup vs baseline: 1.6229x; 1.0638x over previous
//
#include <hip/hip_runtime.h>
#include <hip/hip_bf16.h>
#include <hip/hip_fp8.h>
#include <stdint.h>

#define NTOK 196
#define NB   64
#define CCH  512
#define HID  2048
#define MTOT (NB * NTOK)   // 12544

typedef __attribute__((ext_vector_type(8))) short  short8v;
typedef __attribute__((ext_vector_type(4))) float  float4v;
typedef __attribute__((ext_vector_type(2))) int    int2v;

// ---------------- helpers ----------------

__device__ __forceinline__ void mfma_fp8(float4v& d, int2v a, int2v b) {
  asm("v_mfma_f32_16x16x32_fp8_fp8 %0, %1, %2, %0" : "+v"(d) : "v"(a), "v"(b));
}

__device__ __forceinline__ void gload_lds16(const void* gsrc, void* ldst) {
  __builtin_amdgcn_global_load_lds(
      (const __attribute__((address_space(1))) unsigned int*)gsrc,
      (__attribute__((address_space(3))) unsigned int*)ldst, 16, 0, 0);
}

__device__ __forceinline__ int swz4(int r) { return (r ^ (r >> 2)) & 3; }

__device__ __forceinline__ uint8_t to_fp8(float v) {
  return __hip_fp8_e4m3(v).__x;
}

// ---------------- prep: BN constants ----------------

__global__ void prep_consts(const float* __restrict__ bn_g, const float* __restrict__ bn_b,
                            const float* __restrict__ bn_m, const float* __restrict__ bn_v,
                            const float* __restrict__ fbn_g, const float* __restrict__ fbn_b,
                            const float* __restrict__ fbn_m, const float* __restrict__ fbn_v,
                            float* __restrict__ cst) {
  int c = blockIdx.x * blockDim.x + threadIdx.x;
  if (c < CCH) {
    float i1 = bn_g[c] * rsqrtf(bn_v[c] + 1e-5f);
    cst[c] = i1;
    cst[512 + c] = bn_b[c] - bn_m[c] * i1;
    float i2 = fbn_g[c] * rsqrtf(fbn_v[c] + 1e-5f);
    cst[1024 + c] = i2;
    cst[1536 + c] = fbn_b[c] - fbn_m[c] * i2;
  }
}

// ---------------- weights fp32 -> fp8 e4m3, x16 ----------------

__global__ void cvt_weights(const float* __restrict__ qkv_w, const float* __restrict__ proj_w,
                            const float* __restrict__ fc1_w, const float* __restrict__ fc2_w,
                            uint8_t* __restrict__ qkvb, uint8_t* __restrict__ projb,
                            uint8_t* __restrict__ fc1b, uint8_t* __restrict__ fc2b) {
  int i4 = blockIdx.x * blockDim.x + threadIdx.x;    // unit = 4 floats
  const int nq = 1536 * 512 / 4;
  const int np = 512 * 512 / 4;
  const int n1 = 2048 * 512 / 4;
  const float* src;
  uint8_t* dst;
  int k;
  if (i4 < nq)                { src = qkv_w;  dst = qkvb;  k = i4; }
  else if (i4 < nq + np)      { src = proj_w; dst = projb; k = i4 - nq; }
  else if (i4 < nq + np + n1) { src = fc1_w;  dst = fc1b;  k = i4 - nq - np; }
  else                        { src = fc2_w;  dst = fc2b;  k = i4 - nq - np - n1; }
  float4v v = *(const float4v*)(src + 4 * (size_t)k);
  #pragma unroll
  for (int l = 0; l < 4; ++l) dst[4 * (size_t)k + l] = to_fp8(v[l] * 16.0f);
}

// ---------------- transpose NCHW fp32 -> token-major: fp8 (BN'd) + bf16 (raw) ----------------

__global__ __launch_bounds__(256) void transpose_x(
    const float* __restrict__ x, uint8_t* __restrict__ xnt8,
    __hip_bfloat16* __restrict__ xt, const float* __restrict__ cst) {
  __shared__ float tile[32][33];
  const int n0 = blockIdx.x * 32;
  const int c0 = blockIdx.y * 32;
  const int b  = blockIdx.z;
  const int j = threadIdx.x & 31, i = threadIdx.x >> 5;
  #pragma unroll
  for (int p = 0; p < 4; ++p) {
    int cc = c0 + i + p * 8;
    int n = n0 + j;
    if (n < NTOK) tile[i + p * 8][j] = x[((size_t)b * CCH + cc) * NTOK + n];
  }
  __syncthreads();
  const float s = cst[c0 + j], t = cst[512 + c0 + j];
  #pragma unroll
  for (int p = 0; p < 4; ++p) {
    int n = n0 + i + p * 8;
    int cc = c0 + j;
    if (n < NTOK) {
      float raw = tile[j][i + p * 8];
      size_t o = ((size_t)b * NTOK + n) * CCH + cc;
      xt[o]   = __float2bfloat16(raw);
      xnt8[o] = to_fp8(raw * s + t);
    }
  }
}

// ---------------- fp8 GEMM, R2 schedule: C[M,N] = (A[M,K]*B[N,K]^T)/16 ----------------
// EPI: 0 = qkv: fp8 head-major [sel][h][b][tok][32]
//      1 = proj: x1t = xt + ls1*(v/16+bias)
//      2 = fc1: gelu(v/16+bias)->fp8  3 = fc2: out = x1t + ls2*(v/16+bias) -> NCHW fp32

template<int EPI>
__global__ __launch_bounds__(256, 3) void gemm8f(
    const uint8_t* __restrict__ A, const uint8_t* __restrict__ Bw,
    int N, int K, int NY,
    __hip_bfloat16* __restrict__ outb, uint8_t* __restrict__ out8,
    float* __restrict__ outf,
    const float* __restrict__ bias, const float* __restrict__ ls,
    const __hip_bfloat16* __restrict__ resid) {
  __shared__ char lds[49152];   // 3 bufs x (A 8KB + B 8KB)
  const int tid  = threadIdx.x;
  const int lane = tid & 63;
  const int wave = tid >> 6;

  const int q    = (int)gridDim.x >> 3;
  const int orig = blockIdx.x;
  const int wgid = (orig & 7) * q + (orig >> 3);
  const int bx = wgid / NY;
  const int by = wgid - bx * NY;

  const int m0 = bx * 128;
  const int n0 = by * 128;
  const int wm = (wave >> 1) * 64;
  const int wn = (wave & 1) * 64;
  const int KT = K >> 6;                 // 64-deep K chunks

  float4v acc[4][4] = {};

  auto stage = [&](int buf, int kt) {
    const int kb = kt * 64;
    char* base = lds + buf * 16384;
    #pragma unroll
    for (int i = 0; i < 2; ++i) {
      int L = i * 4096 + tid * 16;
      int row = L >> 6;
      int lc = ((L >> 4) & 3) ^ swz4(row);
      gload_lds16(A + (size_t)(m0 + row) * K + kb + lc * 16, base + L);
    }
    #pragma unroll
    for (int i = 0; i < 2; ++i) {
      int L = i * 4096 + tid * 16;
      int row = L >> 6;
      int lc = ((L >> 4) & 3) ^ swz4(row);
      gload_lds16(Bw + (size_t)(n0 + row) * K + kb + lc * 16, base + 8192 + L);
    }
  };

  auto compute = [&](int buf) {
    const char* bA = lds + buf * 16384;
    const char* bB = bA + 8192;
    const int g = lane >> 4;
    #pragma unroll
    for (int t = 0; t < 2; ++t) {        // two K=32 subtiles per buf
      int2v av[4], bv[4];
      #pragma unroll
      for (int f = 0; f < 4; ++f) {
        int row = wm + f * 16 + (lane & 15);
        int c16 = ((t << 1) | (g >> 1)) ^ swz4(row);
        av[f] = *(const int2v*)(bA + row * 64 + c16 * 16 + (g & 1) * 8);
      }
      #pragma unroll
      for (int j = 0; j < 4; ++j) {
        int row = wn + j * 16 + (lane & 15);
        int c16 = ((t << 1) | (g >> 1)) ^ swz4(row);
        bv[j] = *(const int2v*)(bB + row * 64 + c16 * 16 + (g & 1) * 8);
      }
      #pragma unroll
      for (int i = 0; i < 4; ++i)
        #pragma unroll
        for (int j = 0; j < 4; ++j)
          mfma_fp8(acc[i][j], av[i], bv[j]);
    }
  };

  stage(0, 0);
  stage(1, 1);
  int cur = 0;
  for (int kt = 0; kt < KT - 1; ++kt) {
    asm volatile("s_waitcnt vmcnt(4)" ::: "memory");
    __builtin_amdgcn_s_barrier();
    __builtin_amdgcn_sched_barrier(0);
    if (kt + 2 < KT) {
      int s = cur + 2; if (s >= 3) s -= 3;
      stage(s, kt + 2);
    }
    compute(cur);
    ++cur; if (cur == 3) cur = 0;
  }
  asm volatile("s_waitcnt vmcnt(0)" ::: "memory");
  __builtin_amdgcn_s_barrier();
  __builtin_amdgcn_sched_barrier(0);
  compute(cur);
  asm volatile("s_nop 7\n\ts_nop 7");

  const float RS = 0.0625f;                // undo weight x16

  if (EPI == 0) {
    // fp8 head-major: [sel(3)][h(16)][b(64)][tok(196)][d(32)]
    #pragma unroll
    for (int i = 0; i < 4; ++i)
      #pragma unroll
      for (int j = 0; j < 4; ++j)
        #pragma unroll
        for (int r = 0; r < 4; ++r) {
          int m = m0 + wm + i * 16 + ((lane >> 4) << 2) + r;
          int n = n0 + wn + j * 16 + (lane & 15);
          int bb = m / NTOK, tok = m - bb * NTOK;
          int sel = n >> 9, hh = (n >> 5) & 15, d = n & 31;
          out8[(((size_t)(sel * 16 + hh) * NB + bb) * NTOK + tok) * 32 + d] =
              to_fp8(acc[i][j][r] * RS);
        }
  } else if (EPI == 2) {
    #pragma unroll
    for (int i = 0; i < 4; ++i)
      #pragma unroll
      for (int j = 0; j < 4; ++j)
        #pragma unroll
        for (int r = 0; r < 4; ++r) {
          int m = m0 + wm + i * 16 + ((lane >> 4) << 2) + r;
          int n = n0 + wn + j * 16 + (lane & 15);
          float z = acc[i][j][r] * RS + bias[n];
          float g2 = z / (1.0f + __expf(-1.702f * z));
          out8[(size_t)m * N + n] = to_fp8(g2);
        }
  } else if (EPI == 1) {
    #pragma unroll
    for (int i = 0; i < 4; ++i)
      #pragma unroll
      for (int j = 0; j < 4; ++j)
        #pragma unroll
        for (int r = 0; r < 4; ++r) {
          int m = m0 + wm + i * 16 + ((lane >> 4) << 2) + r;
          int n = n0 + wn + j * 16 + (lane & 15);
          float v = acc[i][j][r] * RS + bias[n];
          v = __bfloat162float(resid[(size_t)m * CCH + n]) + ls[n] * v;
          outb[(size_t)m * CCH + n] = __float2bfloat16(v);
        }
  } else {   // EPI == 3 : epilogue + in-LDS transpose -> NCHW fp32
    float* LT = (float*)lds;   // [64][129] fp32 = 33KB
    #pragma unroll 1
    for (int hh = 0; hh < 2; ++hh) {
      __syncthreads();
      if ((wn >> 6) == hh) {
        #pragma unroll
        for (int i = 0; i < 4; ++i)
          #pragma unroll
          for (int j = 0; j < 4; ++j)
            #pragma unroll
            for (int r = 0; r < 4; ++r) {
              int ml = wm + i * 16 + ((lane >> 4) << 2) + r;
              int nl = j * 16 + (lane & 15);
              int n = n0 + wn + nl;
              float v = acc[i][j][r] * RS + bias[n];
              v = __bfloat162float(resid[(size_t)(m0 + ml) * CCH + n]) + ls[n] * v;
              LT[nl * 129 + ml] = v;
            }
      }
      __syncthreads();
      {
        int ml0 = lane << 1;
        int mg = m0 + ml0;
        int bb0 = mg / NTOK;
        int tt0 = mg - bb0 * NTOK;
        int bb1 = (mg + 1) / NTOK;
        int tt1 = (mg + 1) - bb1 * NTOK;
        size_t base0 = (size_t)bb0 * (CCH * NTOK) + tt0;
        size_t base1 = (size_t)bb1 * (CCH * NTOK) + tt1;
        #pragma unroll
        for (int u = 0; u < 16; ++u) {
          int cr = wave * 16 + u;
          int cg = n0 + hh * 64 + cr;
          float v0 = LT[cr * 129 + ml0];
          float v1 = LT[cr * 129 + ml0 + 1];
          outf[base0 + (size_t)cg * NTOK] = v0;
          outf[base1 + (size_t)cg * NTOK] = v1;
        }
      }
    }
  }
}

// ---------------- attention: fp8 end-to-end, head-major input ----------------
// Block (b,h) reads 3 contiguous 6.3KB chunks. QK^T and PV via mfma_fp8 (K=32).
// P kept unnormalized in fp8; 1/sum applied at output store.

__global__ __launch_bounds__(256, 3) void attn_kernel(
    const uint8_t* __restrict__ qkv8, uint8_t* __restrict__ o_t8) {
  __shared__ char sQ[208 * 48];    // rows stride 48 (2-way bank = free)
  __shared__ char sK[224 * 48];
  __shared__ char sV[32 * 240];    // V^T rows stride 240
  __shared__ char sP[4][16 * 232]; // per-wave P, stride 232 (conflict-free)
  const int tid  = threadIdx.x;
  const int lane = tid & 63;
  const int wave = tid >> 6;
  const int b = blockIdx.x >> 4;
  const int h = blockIdx.x & 15;
  const size_t CHB = 6272;         // 196*32 bytes per (sel,h,b) chunk
  const uint8_t* Qg = qkv8 + ((size_t)(0 * 16 + h) * NB + b) * CHB;
  const uint8_t* Kg = qkv8 + ((size_t)(1 * 16 + h) * NB + b) * CHB;
  const uint8_t* Vg = qkv8 + ((size_t)(2 * 16 + h) * NB + b) * CHB;

  // zero pad regions
  for (int i = tid; i < 144; i += 256) {        // sQ rows 196..207
    int r = i / 12, w = i % 12;
    ((uint32_t*)(sQ + (196 + r) * 48))[w] = 0u;
  }
  for (int i = tid; i < 336; i += 256) {        // sK rows 196..223
    int r = i / 12, w = i % 12;
    ((uint32_t*)(sK + (196 + r) * 48))[w] = 0u;
  }
  for (int i = tid; i < 352; i += 256) {        // sV cols 196..239
    int d = i / 11, w = i % 11;
    ((uint32_t*)(sV + d * 240 + 196))[w] = 0u;
  }

  // stage Q,K (16B chunks -> stride-48 rows)
  for (int c = tid; c < 392; c += 256) {
    int row = c >> 1, hf = c & 1;
    uint4 vq = *(const uint4*)(Qg + c * 16);
    *(uint4*)(sQ + row * 48 + hf * 16) = vq;
    uint4 vk = *(const uint4*)(Kg + c * 16);
    *(uint4*)(sK + row * 48 + hf * 16) = vk;
  }
  // stage V transposed: V[row][d] -> sV[d][row]
  for (int u = tid; u < 784; u += 256) {
    int row = u >> 2, d0 = (u & 3) * 8;
    uint64_t w = *(const uint64_t*)(Vg + (size_t)u * 8);
    #pragma unroll
    for (int e = 0; e < 8; ++e)
      sV[(d0 + e) * 240 + row] = (char)(w >> (8 * e));
  }
  __syncthreads();

  const float scale = 0.17677669529663687f;   // 1/sqrt(32)
  char* Pw = sP[wave];
  const int g = lane >> 4;

  for (int mt = wave; mt < 13; mt += 4) {
    int qrow = mt * 16 + (lane & 15);
    int2v aq = *(const int2v*)(sQ + qrow * 48 + g * 8);

    float4v s[14];
    #pragma unroll
    for (int nt = 0; nt < 14; ++nt) {
      int krow = nt * 16 + (lane & 15);
      int2v bk = *(const int2v*)(sK + krow * 48 + g * 8);
      s[nt] = float4v{0.f, 0.f, 0.f, 0.f};
      mfma_fp8(s[nt], aq, bk);
    }
    asm volatile("s_nop 7\n\ts_nop 7");

    float mx[4] = {-INFINITY, -INFINITY, -INFINITY, -INFINITY};
    #pragma unroll
    for (int nt = 0; nt < 14; ++nt) {
      bool valid = (nt * 16 + (lane & 15)) < NTOK;
      #pragma unroll
      for (int r = 0; r < 4; ++r) {
        float v = valid ? s[nt][r] * scale : -INFINITY;
        s[nt][r] = v;
        mx[r] = fmaxf(mx[r], v);
      }
    }
    #pragma unroll
    for (int off = 1; off < 16; off <<= 1) {
      #pragma unroll
      for (int r = 0; r < 4; ++r) mx[r] = fmaxf(mx[r], __shfl_xor(mx[r], off));
    }
    float sum[4] = {0.f, 0.f, 0.f, 0.f};
    #pragma unroll
    for (int nt = 0; nt < 14; ++nt) {
      #pragma unroll
      for (int r = 0; r < 4; ++r) {
        float e = __expf(s[nt][r] - mx[r]);
        s[nt][r] = e;
        sum[r] += e;
      }
    }
    #pragma unroll
    for (int off = 1; off < 16; off <<= 1) {
      #pragma unroll
      for (int r = 0; r < 4; ++r) sum[r] += __shfl_xor(sum[r], off);
    }
    float rs[4];
    #pragma unroll
    for (int r = 0; r < 4; ++r) rs[r] = 1.0f / sum[r];

    // store P (unnormalized) as fp8
    #pragma unroll
    for (int nt = 0; nt < 14; ++nt) {
      int col = nt * 16 + (lane & 15);
      #pragma unroll
      for (int r = 0; r < 4; ++r) {
        int prow = ((lane >> 4) << 2) + r;
        *(uint8_t*)(Pw + prow * 232 + col) = to_fp8(s[nt][r]);
      }
    }

    float4v o0 = float4v{0.f, 0.f, 0.f, 0.f};
    float4v o1 = float4v{0.f, 0.f, 0.f, 0.f};
    #pragma unroll
    for (int ks = 0; ks < 7; ++ks) {
      int2v pa = *(const int2v*)(Pw + (lane & 15) * 232 + ks * 32 + g * 8);
      int2v v0 = *(const int2v*)(sV + (lane & 15) * 240 + ks * 32 + g * 8);
      int2v v1 = *(const int2v*)(sV + (16 + (lane & 15)) * 240 + ks * 32 + g * 8);
      mfma_fp8(o0, pa, v0);
      mfma_fp8(o1, pa, v1);
    }
    asm volatile("s_nop 7\n\ts_nop 7");

    #pragma unroll
    for (int r = 0; r < 4; ++r) {
      int trow = mt * 16 + ((lane >> 4) << 2) + r;
      if (trow < NTOK) {
        size_t ob = ((size_t)b * NTOK + trow) * CCH + h * 32 + (lane & 15);
        o_t8[ob] = to_fp8(o0[r] * rs[r]);
        o_t8[ob + 16] = to_fp8(o1[r] * rs[r]);
      }
    }
  }
}

// ---------------- depthwise 7x7 conv, token-major (+BN in, +fBN out, fp8 out) ----------------

__global__ __launch_bounds__(448) void dwconv_tm(
    const __hip_bfloat16* __restrict__ x1t, const float* __restrict__ dw_w,
    const float* __restrict__ cst, uint8_t* __restrict__ yt8) {
  __shared__ float img[196][32];
  __shared__ float wgt[49][32];
  const int tid = threadIdx.x;
  const int b  = blockIdx.x >> 4;
  const int cb = (blockIdx.x & 15) * 32;
  const int c  = tid & 31;
  const int gc = cb + c;
  const float s = cst[gc], t0 = cst[512 + gc];
  #pragma unroll
  for (int k = 0; k < 14; ++k) {
    int p = (tid >> 5) + k * 14;
    img[p][c] = __bfloat162float(x1t[((size_t)b * NTOK + p) * CCH + gc]) * s + t0;
  }
  for (int i = tid; i < 49 * 32; i += 448) {
    int tap = i >> 5, cc = i & 31;
    wgt[tap][cc] = dw_w[(cb + cc) * 49 + tap];
  }
  __syncthreads();

  const int px = tid >> 5;        // 0..13
  float out[14];
  #pragma unroll
  for (int i = 0; i < 14; ++i) out[i] = 0.f;
  #pragma unroll 1
  for (int row = 0; row < 14; ++row) {
    float v[7];
    #pragma unroll
    for (int dx = 0; dx < 7; ++dx) {
      int ix = px + dx - 3;
      v[dx] = ((unsigned)ix < 14u) ? img[row * 14 + ix][c] : 0.f;
    }
    #pragma unroll
    for (int kk = 0; kk < 7; ++kk) {
      int py = row + 3 - kk;
      if (py >= 0 && py < 14) {
        float hsum = 0.f;
        #pragma unroll
        for (int dx = 0; dx < 7; ++dx) hsum = fmaf(v[dx], wgt[kk * 7 + dx][c], hsum);
        out[py] += hsum;
      }
    }
  }
  const float fs = cst[1024 + gc], ft = cst[1536 + gc];
  #pragma unroll
  for (int py = 0; py < 14; ++py)
    yt8[((size_t)b * NTOK + py * 14 + px) * CCH + gc] = to_fp8(out[py] * fs + ft);
}

// ---------------- launch ----------------

extern "C" void kernel_launch(void* const* d_in, const int* in_sizes, int n_in,
                              void* d_out, int out_size, void* d_ws, size_t ws_size,
                              hipStream_t stream) {
  const float* x      = (const float*)d_in[0];
  const float* bn_g   = (const float*)d_in[1];
  const float* bn_b   = (const float*)d_in[2];
  const float* bn_m   = (const float*)d_in[3];
  const float* bn_v   = (const float*)d_in[4];
  const float* qkv_w  = (const float*)d_in[5];
  const float* proj_w = (const float*)d_in[6];
  const float* proj_b = (const float*)d_in[7];
  const float* dw_w   = (const float*)d_in[8];
  const float* fbn_g  = (const float*)d_in[9];
  const float* fbn_b  = (const float*)d_in[10];
  const float* fbn_m  = (const float*)d_in[11];
  const float* fbn_v  = (const float*)d_in[12];
  const float* fc1_w  = (const float*)d_in[13];
  const float* fc1_b  = (const float*)d_in[14];
  const float* fc2_w  = (const float*)d_in[15];
  const float* fc2_b  = (const float*)d_in[16];
  const float* ls1    = (const float*)d_in[17];
  const float* ls2    = (const float*)d_in[18];

  char* ws = (char*)d_ws;
  float* cst             = (float*)ws;                        // 8 KB
  uint8_t* qkvb8         = (uint8_t*)(ws + 32768);            // 768 KB
  uint8_t* projb8        = (uint8_t*)(ws + 819200);           // 256 KB
  uint8_t* fc1b8         = (uint8_t*)(ws + 1081344);          // 1 MB
  uint8_t* fc2b8         = (uint8_t*)(ws + 2129920);          // 1 MB
  uint8_t* xnt8          = (uint8_t*)(ws + 3178496);          // 6.4 MB (fp8 BN'd x)
  __hip_bfloat16* xt     = (__hip_bfloat16*)(ws + 9601024);   // 12.85 MB (raw x, resid)
  uint8_t* qkv8          = (uint8_t*)(ws + 22446080);         // 19.3 MB head-major fp8
  uint8_t* ot8           = (uint8_t*)(ws + 60981248);         // 6.4 MB
  __hip_bfloat16* x1t    = (__hip_bfloat16*)(ws + 67403776);  // 12.85 MB
  uint8_t* yt8           = (uint8_t*)(ws + 80248832);         // 6.4 MB (end 86.7 MB)
  uint8_t* h8            = (uint8_t*)(ws + 3178496);          // 25.7 MB overlay (xnt8/xt/qkv8 dead)

  prep_consts<<<dim3(2), dim3(256), 0, stream>>>(bn_g, bn_b, bn_m, bn_v,
                                                 fbn_g, fbn_b, fbn_m, fbn_v, cst);
  cvt_weights<<<dim3(3072), dim3(256), 0, stream>>>(qkv_w, proj_w, fc1_w, fc2_w,
                                                    qkvb8, projb8, fc1b8, fc2b8);
  transpose_x<<<dim3(7, 16, 64), dim3(256), 0, stream>>>(x, xnt8, xt, cst);
  // QKV: M=12544, N=1536, K=512 ; 128x128 -> 98*12 = 1176 blocks ; fp8 head-major out
  gemm8f<0><<<dim3(1176), dim3(256), 0, stream>>>(xnt8, qkvb8, 1536, 512, 12,
                                                  nullptr, qkv8, nullptr, nullptr, nullptr, nullptr);
  attn_kernel<<<dim3(1024), dim3(256), 0, stream>>>(qkv8, ot8);
  // proj: N=512, K=512 ; 98*4 = 392 blocks
  gemm8f<1><<<dim3(392), dim3(256), 0, stream>>>(ot8, projb8, 512, 512, 4,
                                                 x1t, nullptr, nullptr, proj_b, ls1, xt);
  dwconv_tm<<<dim3(1024), dim3(448), 0, stream>>>(x1t, dw_w, cst, yt8);
  // fc1: N=2048, K=512 ; 98*16 = 1568 blocks
  gemm8f<2><<<dim3(1568), dim3(256), 0, stream>>>(yt8, fc1b8, 2048, 512, 16,
                                                  nullptr, h8, nullptr, fc1_b, nullptr, nullptr);
  // fc2: N=512, K=2048 ; 392 blocks ; NCHW fp32 out
  gemm8f<3><<<dim3(392), dim3(256), 0, stream>>>(h8, fc2b8, 512, 2048, 4,
                                                 nullptr, nullptr, (float*)d_out, fc2_b, ls2, x1t);
}

// Round 14
// 195.170 us; speedup vs baseline: 1.7095x; 1.0534x over previous
//
#include <hip/hip_runtime.h>
#include <hip/hip_bf16.h>
#include <hip/hip_fp8.h>
#include <stdint.h>

#define NTOK 196
#define NB   64
#define CCH  512
#define HID  2048
#define MTOT (NB * NTOK)   // 12544

typedef __attribute__((ext_vector_type(8))) short  short8v;
typedef __attribute__((ext_vector_type(4))) float  float4v;
typedef __attribute__((ext_vector_type(2))) int    int2v;

// ---------------- helpers ----------------

__device__ __forceinline__ void mfma_fp8(float4v& d, int2v a, int2v b) {
  asm("v_mfma_f32_16x16x32_fp8_fp8 %0, %1, %2, %0" : "+v"(d) : "v"(a), "v"(b));
}

__device__ __forceinline__ void gload_lds16(const void* gsrc, void* ldst) {
  __builtin_amdgcn_global_load_lds(
      (const __attribute__((address_space(1))) unsigned int*)gsrc,
      (__attribute__((address_space(3))) unsigned int*)ldst, 16, 0, 0);
}

__device__ __forceinline__ int swz4(int r) { return (r ^ (r >> 2)) & 3; }

// hardware packed fp8 conversion: byte0 = fp8(a), byte1 = fp8(b)
__device__ __forceinline__ uint32_t cvt2_fp8(float a, float b) {
  uint32_t d;
  asm("v_cvt_pk_fp8_f32 %0, %1, %2" : "=v"(d) : "v"(a), "v"(b));
  return d;
}

__device__ __forceinline__ uint8_t to_fp8(float v) {   // scalar fallback (host prep only)
  return __hip_fp8_e4m3(v).__x;
}

// ---------------- prep: BN constants ----------------

__global__ void prep_consts(const float* __restrict__ bn_g, const float* __restrict__ bn_b,
                            const float* __restrict__ bn_m, const float* __restrict__ bn_v,
                            const float* __restrict__ fbn_g, const float* __restrict__ fbn_b,
                            const float* __restrict__ fbn_m, const float* __restrict__ fbn_v,
                            float* __restrict__ cst) {
  int c = blockIdx.x * blockDim.x + threadIdx.x;
  if (c < CCH) {
    float i1 = bn_g[c] * rsqrtf(bn_v[c] + 1e-5f);
    cst[c] = i1;
    cst[512 + c] = bn_b[c] - bn_m[c] * i1;
    float i2 = fbn_g[c] * rsqrtf(fbn_v[c] + 1e-5f);
    cst[1024 + c] = i2;
    cst[1536 + c] = fbn_b[c] - fbn_m[c] * i2;
  }
}

// ---------------- weights fp32 -> fp8 e4m3, x16 ----------------

__global__ void cvt_weights(const float* __restrict__ qkv_w, const float* __restrict__ proj_w,
                            const float* __restrict__ fc1_w, const float* __restrict__ fc2_w,
                            uint8_t* __restrict__ qkvb, uint8_t* __restrict__ projb,
                            uint8_t* __restrict__ fc1b, uint8_t* __restrict__ fc2b) {
  int i4 = blockIdx.x * blockDim.x + threadIdx.x;    // unit = 4 floats
  const int nq = 1536 * 512 / 4;
  const int np = 512 * 512 / 4;
  const int n1 = 2048 * 512 / 4;
  const float* src;
  uint8_t* dst;
  int k;
  if (i4 < nq)                { src = qkv_w;  dst = qkvb;  k = i4; }
  else if (i4 < nq + np)      { src = proj_w; dst = projb; k = i4 - nq; }
  else if (i4 < nq + np + n1) { src = fc1_w;  dst = fc1b;  k = i4 - nq - np; }
  else                        { src = fc2_w;  dst = fc2b;  k = i4 - nq - np - n1; }
  float4v v = *(const float4v*)(src + 4 * (size_t)k);
  uint32_t w0 = cvt2_fp8(v[0] * 16.0f, v[1] * 16.0f);
  uint32_t w1 = cvt2_fp8(v[2] * 16.0f, v[3] * 16.0f);
  *(uint16_t*)(dst + 4 * (size_t)k)     = (uint16_t)w0;
  *(uint16_t*)(dst + 4 * (size_t)k + 2) = (uint16_t)w1;
}

// ---------------- transpose NCHW fp32 -> token-major: fp8 (BN'd) + bf16 (raw) ----------------

__global__ __launch_bounds__(256) void transpose_x(
    const float* __restrict__ x, uint8_t* __restrict__ xnt8,
    __hip_bfloat16* __restrict__ xt, const float* __restrict__ cst) {
  __shared__ float tile[32][33];
  const int n0 = blockIdx.x * 32;
  const int c0 = blockIdx.y * 32;
  const int b  = blockIdx.z;
  const int j = threadIdx.x & 31, i = threadIdx.x >> 5;
  #pragma unroll
  for (int p = 0; p < 4; ++p) {
    int cc = c0 + i + p * 8;
    int n = n0 + j;
    if (n < NTOK) tile[i + p * 8][j] = x[((size_t)b * CCH + cc) * NTOK + n];
  }
  __syncthreads();
  const float s = cst[c0 + j], t = cst[512 + c0 + j];
  float bn[4];
  size_t off[4];
  bool ok[4];
  #pragma unroll
  for (int p = 0; p < 4; ++p) {
    int n = n0 + i + p * 8;
    int cc = c0 + j;
    ok[p] = (n < NTOK);
    if (ok[p]) {
      float raw = tile[j][i + p * 8];
      size_t o = ((size_t)b * NTOK + n) * CCH + cc;
      xt[o] = __float2bfloat16(raw);
      bn[p] = raw * s + t;
      off[p] = o;
    }
  }
  uint32_t w0 = cvt2_fp8(bn[0], bn[1]);
  uint32_t w1 = cvt2_fp8(bn[2], bn[3]);
  if (ok[0]) xnt8[off[0]] = (uint8_t)w0;
  if (ok[1]) xnt8[off[1]] = (uint8_t)(w0 >> 8);
  if (ok[2]) xnt8[off[2]] = (uint8_t)w1;
  if (ok[3]) xnt8[off[3]] = (uint8_t)(w1 >> 8);
}

// ---------------- fp8 GEMM, R2 schedule: C[M,N] = (A[M,K]*B[N,K]^T)/16 ----------------
// EPI: 0 = qkv: fp8 head-major [sel][h][b][tok][32]
//      1 = proj: x1t = xt + ls1*(v/16+bias)
//      2 = fc1: gelu(v/16+bias)->fp8  3 = fc2: out = x1t + ls2*(v/16+bias) -> NCHW fp32

template<int EPI>
__global__ __launch_bounds__(256, 3) void gemm8f(
    const uint8_t* __restrict__ A, const uint8_t* __restrict__ Bw,
    int N, int K, int NY,
    __hip_bfloat16* __restrict__ outb, uint8_t* __restrict__ out8,
    float* __restrict__ outf,
    const float* __restrict__ bias, const float* __restrict__ ls,
    const __hip_bfloat16* __restrict__ resid) {
  __shared__ char lds[49152];   // 3 bufs x (A 8KB + B 8KB)
  const int tid  = threadIdx.x;
  const int lane = tid & 63;
  const int wave = tid >> 6;

  const int q    = (int)gridDim.x >> 3;
  const int orig = blockIdx.x;
  const int wgid = (orig & 7) * q + (orig >> 3);
  const int bx = wgid / NY;
  const int by = wgid - bx * NY;

  const int m0 = bx * 128;
  const int n0 = by * 128;
  const int wm = (wave >> 1) * 64;
  const int wn = (wave & 1) * 64;
  const int KT = K >> 6;                 // 64-deep K chunks

  float4v acc[4][4] = {};

  auto stage = [&](int buf, int kt) {
    const int kb = kt * 64;
    char* base = lds + buf * 16384;
    #pragma unroll
    for (int i = 0; i < 2; ++i) {
      int L = i * 4096 + tid * 16;
      int row = L >> 6;
      int lc = ((L >> 4) & 3) ^ swz4(row);
      gload_lds16(A + (size_t)(m0 + row) * K + kb + lc * 16, base + L);
    }
    #pragma unroll
    for (int i = 0; i < 2; ++i) {
      int L = i * 4096 + tid * 16;
      int row = L >> 6;
      int lc = ((L >> 4) & 3) ^ swz4(row);
      gload_lds16(Bw + (size_t)(n0 + row) * K + kb + lc * 16, base + 8192 + L);
    }
  };

  auto compute = [&](int buf) {
    const char* bA = lds + buf * 16384;
    const char* bB = bA + 8192;
    const int g = lane >> 4;
    #pragma unroll
    for (int t = 0; t < 2; ++t) {        // two K=32 subtiles per buf
      int2v av[4], bv[4];
      #pragma unroll
      for (int f = 0; f < 4; ++f) {
        int row = wm + f * 16 + (lane & 15);
        int c16 = ((t << 1) | (g >> 1)) ^ swz4(row);
        av[f] = *(const int2v*)(bA + row * 64 + c16 * 16 + (g & 1) * 8);
      }
      #pragma unroll
      for (int j = 0; j < 4; ++j) {
        int row = wn + j * 16 + (lane & 15);
        int c16 = ((t << 1) | (g >> 1)) ^ swz4(row);
        bv[j] = *(const int2v*)(bB + row * 64 + c16 * 16 + (g & 1) * 8);
      }
      #pragma unroll
      for (int i = 0; i < 4; ++i)
        #pragma unroll
        for (int j = 0; j < 4; ++j)
          mfma_fp8(acc[i][j], av[i], bv[j]);
    }
  };

  stage(0, 0);
  stage(1, 1);
  int cur = 0;
  for (int kt = 0; kt < KT - 1; ++kt) {
    asm volatile("s_waitcnt vmcnt(4)" ::: "memory");
    __builtin_amdgcn_s_barrier();
    __builtin_amdgcn_sched_barrier(0);
    if (kt + 2 < KT) {
      int s = cur + 2; if (s >= 3) s -= 3;
      stage(s, kt + 2);
    }
    compute(cur);
    ++cur; if (cur == 3) cur = 0;
  }
  asm volatile("s_waitcnt vmcnt(0)" ::: "memory");
  __builtin_amdgcn_s_barrier();
  __builtin_amdgcn_sched_barrier(0);
  compute(cur);
  asm volatile("s_nop 7\n\ts_nop 7");

  const float RS = 0.0625f;                // undo weight x16

  if (EPI == 0) {
    // fp8 head-major: [sel(3)][h(16)][b(64)][tok(196)][d(32)]
    #pragma unroll
    for (int i = 0; i < 4; ++i)
      #pragma unroll
      for (int j = 0; j < 4; ++j)
        #pragma unroll
        for (int r = 0; r < 4; r += 2) {
          int m = m0 + wm + i * 16 + ((lane >> 4) << 2) + r;
          int n = n0 + wn + j * 16 + (lane & 15);
          int bb = m / NTOK, tok = m - bb * NTOK;
          int bb2 = (m + 1) / NTOK, tok2 = (m + 1) - bb2 * NTOK;
          int sel = n >> 9, hh = (n >> 5) & 15, d = n & 31;
          uint32_t w = cvt2_fp8(acc[i][j][r] * RS, acc[i][j][r + 1] * RS);
          out8[(((size_t)(sel * 16 + hh) * NB + bb) * NTOK + tok) * 32 + d]  = (uint8_t)w;
          out8[(((size_t)(sel * 16 + hh) * NB + bb2) * NTOK + tok2) * 32 + d] = (uint8_t)(w >> 8);
        }
  } else if (EPI == 2) {
    #pragma unroll
    for (int i = 0; i < 4; ++i)
      #pragma unroll
      for (int j = 0; j < 4; ++j)
        #pragma unroll
        for (int r = 0; r < 4; r += 2) {
          int m = m0 + wm + i * 16 + ((lane >> 4) << 2) + r;
          int n = n0 + wn + j * 16 + (lane & 15);
          float z0 = acc[i][j][r] * RS + bias[n];
          float z1 = acc[i][j][r + 1] * RS + bias[n];
          float g0 = z0 / (1.0f + __expf(-1.702f * z0));
          float g1 = z1 / (1.0f + __expf(-1.702f * z1));
          uint32_t w = cvt2_fp8(g0, g1);
          out8[(size_t)m * N + n]       = (uint8_t)w;
          out8[(size_t)(m + 1) * N + n] = (uint8_t)(w >> 8);
        }
  } else if (EPI == 1) {
    #pragma unroll
    for (int i = 0; i < 4; ++i)
      #pragma unroll
      for (int j = 0; j < 4; ++j)
        #pragma unroll
        for (int r = 0; r < 4; ++r) {
          int m = m0 + wm + i * 16 + ((lane >> 4) << 2) + r;
          int n = n0 + wn + j * 16 + (lane & 15);
          float v = acc[i][j][r] * RS + bias[n];
          v = __bfloat162float(resid[(size_t)m * CCH + n]) + ls[n] * v;
          outb[(size_t)m * CCH + n] = __float2bfloat16(v);
        }
  } else {   // EPI == 3 : epilogue + in-LDS transpose -> NCHW fp32
    float* LT = (float*)lds;   // [64][129] fp32 = 33KB
    #pragma unroll 1
    for (int hh = 0; hh < 2; ++hh) {
      __syncthreads();
      if ((wn >> 6) == hh) {
        #pragma unroll
        for (int i = 0; i < 4; ++i)
          #pragma unroll
          for (int j = 0; j < 4; ++j)
            #pragma unroll
            for (int r = 0; r < 4; ++r) {
              int ml = wm + i * 16 + ((lane >> 4) << 2) + r;
              int nl = j * 16 + (lane & 15);
              int n = n0 + wn + nl;
              float v = acc[i][j][r] * RS + bias[n];
              v = __bfloat162float(resid[(size_t)(m0 + ml) * CCH + n]) + ls[n] * v;
              LT[nl * 129 + ml] = v;
            }
      }
      __syncthreads();
      {
        int ml0 = lane << 1;
        int mg = m0 + ml0;
        int bb0 = mg / NTOK;
        int tt0 = mg - bb0 * NTOK;
        int bb1 = (mg + 1) / NTOK;
        int tt1 = (mg + 1) - bb1 * NTOK;
        size_t base0 = (size_t)bb0 * (CCH * NTOK) + tt0;
        size_t base1 = (size_t)bb1 * (CCH * NTOK) + tt1;
        #pragma unroll
        for (int u = 0; u < 16; ++u) {
          int cr = wave * 16 + u;
          int cg = n0 + hh * 64 + cr;
          float v0 = LT[cr * 129 + ml0];
          float v1 = LT[cr * 129 + ml0 + 1];
          outf[base0 + (size_t)cg * NTOK] = v0;
          outf[base1 + (size_t)cg * NTOK] = v1;
        }
      }
    }
  }
}

// ---------------- attention: fp8 end-to-end, head-major input ----------------

__global__ __launch_bounds__(256, 3) void attn_kernel(
    const uint8_t* __restrict__ qkv8, uint8_t* __restrict__ o_t8) {
  __shared__ char sQ[208 * 48];    // rows stride 48 (2-way bank = free)
  __shared__ char sK[224 * 48];
  __shared__ char sV[32 * 240];    // V^T rows stride 240
  __shared__ char sP[4][16 * 232]; // per-wave P, stride 232
  const int tid  = threadIdx.x;
  const int lane = tid & 63;
  const int wave = tid >> 6;
  const int b = blockIdx.x >> 4;
  const int h = blockIdx.x & 15;
  const size_t CHB = 6272;         // 196*32 bytes per (sel,h,b) chunk
  const uint8_t* Qg = qkv8 + ((size_t)(0 * 16 + h) * NB + b) * CHB;
  const uint8_t* Kg = qkv8 + ((size_t)(1 * 16 + h) * NB + b) * CHB;
  const uint8_t* Vg = qkv8 + ((size_t)(2 * 16 + h) * NB + b) * CHB;

  for (int i = tid; i < 144; i += 256) {
    int r = i / 12, w = i % 12;
    ((uint32_t*)(sQ + (196 + r) * 48))[w] = 0u;
  }
  for (int i = tid; i < 336; i += 256) {
    int r = i / 12, w = i % 12;
    ((uint32_t*)(sK + (196 + r) * 48))[w] = 0u;
  }
  for (int i = tid; i < 352; i += 256) {
    int d = i / 11, w = i % 11;
    ((uint32_t*)(sV + d * 240 + 196))[w] = 0u;
  }

  for (int c = tid; c < 392; c += 256) {
    int row = c >> 1, hf = c & 1;
    uint4 vq = *(const uint4*)(Qg + c * 16);
    *(uint4*)(sQ + row * 48 + hf * 16) = vq;
    uint4 vk = *(const uint4*)(Kg + c * 16);
    *(uint4*)(sK + row * 48 + hf * 16) = vk;
  }
  for (int u = tid; u < 784; u += 256) {
    int row = u >> 2, d0 = (u & 3) * 8;
    uint64_t w = *(const uint64_t*)(Vg + (size_t)u * 8);
    #pragma unroll
    for (int e = 0; e < 8; ++e)
      sV[(d0 + e) * 240 + row] = (char)(w >> (8 * e));
  }
  __syncthreads();

  const float scale = 0.17677669529663687f;   // 1/sqrt(32)
  char* Pw = sP[wave];
  const int g = lane >> 4;

  for (int mt = wave; mt < 13; mt += 4) {
    int qrow = mt * 16 + (lane & 15);
    int2v aq = *(const int2v*)(sQ + qrow * 48 + g * 8);

    float4v s[14];
    #pragma unroll
    for (int nt = 0; nt < 14; ++nt) {
      int krow = nt * 16 + (lane & 15);
      int2v bk = *(const int2v*)(sK + krow * 48 + g * 8);
      s[nt] = float4v{0.f, 0.f, 0.f, 0.f};
      mfma_fp8(s[nt], aq, bk);
    }
    asm volatile("s_nop 7\n\ts_nop 7");

    float mx[4] = {-INFINITY, -INFINITY, -INFINITY, -INFINITY};
    #pragma unroll
    for (int nt = 0; nt < 14; ++nt) {
      bool valid = (nt * 16 + (lane & 15)) < NTOK;
      #pragma unroll
      for (int r = 0; r < 4; ++r) {
        float v = valid ? s[nt][r] * scale : -INFINITY;
        s[nt][r] = v;
        mx[r] = fmaxf(mx[r], v);
      }
    }
    #pragma unroll
    for (int off = 1; off < 16; off <<= 1) {
      #pragma unroll
      for (int r = 0; r < 4; ++r) mx[r] = fmaxf(mx[r], __shfl_xor(mx[r], off));
    }
    float sum[4] = {0.f, 0.f, 0.f, 0.f};
    #pragma unroll
    for (int nt = 0; nt < 14; ++nt) {
      #pragma unroll
      for (int r = 0; r < 4; ++r) {
        float e = __expf(s[nt][r] - mx[r]);
        s[nt][r] = e;
        sum[r] += e;
      }
    }
    #pragma unroll
    for (int off = 1; off < 16; off <<= 1) {
      #pragma unroll
      for (int r = 0; r < 4; ++r) sum[r] += __shfl_xor(sum[r], off);
    }
    float rs[4];
    #pragma unroll
    for (int r = 0; r < 4; ++r) rs[r] = 1.0f / sum[r];

    // store P (unnormalized) as fp8 — hardware packed conversion
    #pragma unroll
    for (int nt = 0; nt < 14; ++nt) {
      int col = nt * 16 + (lane & 15);
      #pragma unroll
      for (int r = 0; r < 4; r += 2) {
        int prow = ((lane >> 4) << 2) + r;
        uint32_t w = cvt2_fp8(s[nt][r], s[nt][r + 1]);
        *(uint8_t*)(Pw + prow * 232 + col)       = (uint8_t)w;
        *(uint8_t*)(Pw + (prow + 1) * 232 + col) = (uint8_t)(w >> 8);
      }
    }

    float4v o0 = float4v{0.f, 0.f, 0.f, 0.f};
    float4v o1 = float4v{0.f, 0.f, 0.f, 0.f};
    #pragma unroll
    for (int ks = 0; ks < 7; ++ks) {
      int2v pa = *(const int2v*)(Pw + (lane & 15) * 232 + ks * 32 + g * 8);
      int2v v0 = *(const int2v*)(sV + (lane & 15) * 240 + ks * 32 + g * 8);
      int2v v1 = *(const int2v*)(sV + (16 + (lane & 15)) * 240 + ks * 32 + g * 8);
      mfma_fp8(o0, pa, v0);
      mfma_fp8(o1, pa, v1);
    }
    asm volatile("s_nop 7\n\ts_nop 7");

    #pragma unroll
    for (int r = 0; r < 4; ++r) {
      int trow = mt * 16 + ((lane >> 4) << 2) + r;
      if (trow < NTOK) {
        size_t ob = ((size_t)b * NTOK + trow) * CCH + h * 32 + (lane & 15);
        uint32_t w = cvt2_fp8(o0[r] * rs[r], o1[r] * rs[r]);
        o_t8[ob]      = (uint8_t)w;
        o_t8[ob + 16] = (uint8_t)(w >> 8);
      }
    }
  }
}

// ---------------- depthwise 7x7 conv, token-major (+BN in, +fBN out, fp8 out) ----------------

__global__ __launch_bounds__(448) void dwconv_tm(
    const __hip_bfloat16* __restrict__ x1t, const float* __restrict__ dw_w,
    const float* __restrict__ cst, uint8_t* __restrict__ yt8) {
  __shared__ float img[196][32];
  __shared__ float wgt[49][32];
  const int tid = threadIdx.x;
  const int b  = blockIdx.x >> 4;
  const int cb = (blockIdx.x & 15) * 32;
  const int c  = tid & 31;
  const int gc = cb + c;
  const float s = cst[gc], t0 = cst[512 + gc];
  #pragma unroll
  for (int k = 0; k < 14; ++k) {
    int p = (tid >> 5) + k * 14;
    img[p][c] = __bfloat162float(x1t[((size_t)b * NTOK + p) * CCH + gc]) * s + t0;
  }
  for (int i = tid; i < 49 * 32; i += 448) {
    int tap = i >> 5, cc = i & 31;
    wgt[tap][cc] = dw_w[(cb + cc) * 49 + tap];
  }
  __syncthreads();

  const int px = tid >> 5;        // 0..13
  float out[14];
  #pragma unroll
  for (int i = 0; i < 14; ++i) out[i] = 0.f;
  #pragma unroll 1
  for (int row = 0; row < 14; ++row) {
    float v[7];
    #pragma unroll
    for (int dx = 0; dx < 7; ++dx) {
      int ix = px + dx - 3;
      v[dx] = ((unsigned)ix < 14u) ? img[row * 14 + ix][c] : 0.f;
    }
    #pragma unroll
    for (int kk = 0; kk < 7; ++kk) {
      int py = row + 3 - kk;
      if (py >= 0 && py < 14) {
        float hsum = 0.f;
        #pragma unroll
        for (int dx = 0; dx < 7; ++dx) hsum = fmaf(v[dx], wgt[kk * 7 + dx][c], hsum);
        out[py] += hsum;
      }
    }
  }
  const float fs = cst[1024 + gc], ft = cst[1536 + gc];
  #pragma unroll
  for (int py = 0; py < 14; py += 2) {
    uint32_t w = cvt2_fp8(out[py] * fs + ft, out[py + 1] * fs + ft);
    yt8[((size_t)b * NTOK + py * 14 + px) * CCH + gc]       = (uint8_t)w;
    yt8[((size_t)b * NTOK + (py + 1) * 14 + px) * CCH + gc] = (uint8_t)(w >> 8);
  }
}

// ---------------- launch ----------------

extern "C" void kernel_launch(void* const* d_in, const int* in_sizes, int n_in,
                              void* d_out, int out_size, void* d_ws, size_t ws_size,
                              hipStream_t stream) {
  const float* x      = (const float*)d_in[0];
  const float* bn_g   = (const float*)d_in[1];
  const float* bn_b   = (const float*)d_in[2];
  const float* bn_m   = (const float*)d_in[3];
  const float* bn_v   = (const float*)d_in[4];
  const float* qkv_w  = (const float*)d_in[5];
  const float* proj_w = (const float*)d_in[6];
  const float* proj_b = (const float*)d_in[7];
  const float* dw_w   = (const float*)d_in[8];
  const float* fbn_g  = (const float*)d_in[9];
  const float* fbn_b  = (const float*)d_in[10];
  const float* fbn_m  = (const float*)d_in[11];
  const float* fbn_v  = (const float*)d_in[12];
  const float* fc1_w  = (const float*)d_in[13];
  const float* fc1_b  = (const float*)d_in[14];
  const float* fc2_w  = (const float*)d_in[15];
  const float* fc2_b  = (const float*)d_in[16];
  const float* ls1    = (const float*)d_in[17];
  const float* ls2    = (const float*)d_in[18];

  char* ws = (char*)d_ws;
  float* cst             = (float*)ws;                        // 8 KB
  uint8_t* qkvb8         = (uint8_t*)(ws + 32768);            // 768 KB
  uint8_t* projb8        = (uint8_t*)(ws + 819200);           // 256 KB
  uint8_t* fc1b8         = (uint8_t*)(ws + 1081344);          // 1 MB
  uint8_t* fc2b8         = (uint8_t*)(ws + 2129920);          // 1 MB
  uint8_t* xnt8          = (uint8_t*)(ws + 3178496);          // 6.4 MB (fp8 BN'd x)
  __hip_bfloat16* xt     = (__hip_bfloat16*)(ws + 9601024);   // 12.85 MB (raw x, resid)
  uint8_t* qkv8          = (uint8_t*)(ws + 22446080);         // 19.3 MB head-major fp8
  uint8_t* ot8           = (uint8_t*)(ws + 60981248);         // 6.4 MB
  __hip_bfloat16* x1t    = (__hip_bfloat16*)(ws + 67403776);  // 12.85 MB
  uint8_t* yt8           = (uint8_t*)(ws + 80248832);         // 6.4 MB (end 86.7 MB)
  uint8_t* h8            = (uint8_t*)(ws + 3178496);          // 25.7 MB overlay (xnt8/xt/qkv8 dead)

  prep_consts<<<dim3(2), dim3(256), 0, stream>>>(bn_g, bn_b, bn_m, bn_v,
                                                 fbn_g, fbn_b, fbn_m, fbn_v, cst);
  cvt_weights<<<dim3(3072), dim3(256), 0, stream>>>(qkv_w, proj_w, fc1_w, fc2_w,
                                                    qkvb8, projb8, fc1b8, fc2b8);
  transpose_x<<<dim3(7, 16, 64), dim3(256), 0, stream>>>(x, xnt8, xt, cst);
  // QKV: M=12544, N=1536, K=512 ; 128x128 -> 98*12 = 1176 blocks ; fp8 head-major out
  gemm8f<0><<<dim3(1176), dim3(256), 0, stream>>>(xnt8, qkvb8, 1536, 512, 12,
                                                  nullptr, qkv8, nullptr, nullptr, nullptr, nullptr);
  attn_kernel<<<dim3(1024), dim3(256), 0, stream>>>(qkv8, ot8);
  // proj: N=512, K=512 ; 98*4 = 392 blocks
  gemm8f<1><<<dim3(392), dim3(256), 0, stream>>>(ot8, projb8, 512, 512, 4,
                                                 x1t, nullptr, nullptr, proj_b, ls1, xt);
  dwconv_tm<<<dim3(1024), dim3(448), 0, stream>>>(x1t, dw_w, cst, yt8);
  // fc1: N=2048, K=512 ; 98*16 = 1568 blocks
  gemm8f<2><<<dim3(1568), dim3(256), 0, stream>>>(yt8, fc1b8, 2048, 512, 16,
                                                  nullptr, h8, nullptr, fc1_b, nullptr, nullptr);
  // fc2: N=512, K=2048 ; 392 blocks ; NCHW fp32 out
  gemm8f<3><<<dim3(392), dim3(256), 0, stream>>>(h8, fc2b8, 512, 2048, 4,
                                                 nullptr, nullptr, (float*)d_out, fc2_b, ls2, x1t);
}